// Round 8
// baseline (3869.876 us; speedup 1.0000x reference)
//
#include <hip/hip_runtime.h>

// ---------------------------------------------------------------------------
// SequenceTaggle: hierarchical GRU (sentence enc -> doc enc) on MI355X.
// V=32000 E=256 H=256 O=2 S=96 T=32 B=32, N = S*B = 3072.
// DEVICE DTYPES: float tensors f32; tokens int32; output f32.
// Internal: bf16 MFMA, f32 accumulation.
// pgru: persistent GRU, Wh pinned in VGPRs (asm + waves_per_eu(1,2) so the
// allocator has a 512-VGPR budget and cannot spill), raw s_barrier (no vmcnt
// drain), xw prefetched 1 step ahead. Sentence bi-GRU dir-sequential.
// ---------------------------------------------------------------------------

typedef __bf16 bf16;
typedef __bf16 bf16x8 __attribute__((ext_vector_type(8)));
typedef __bf16 bf16x4 __attribute__((ext_vector_type(4)));
typedef float  f32x4  __attribute__((ext_vector_type(4)));

static __device__ __forceinline__ f32x4 mfma16(bf16x8 a, bf16x8 b, f32x4 c) {
  // A: lane row = lane&15, k = (lane>>4)*8 + j ; B: lane col = lane&15, same k
  // D: col = lane&15, row = (lane>>4)*4 + reg
  return __builtin_amdgcn_mfma_f32_16x16x32_bf16(a, b, c, 0, 0, 0);
}
static __device__ __forceinline__ float sigm(float x) { return 1.f / (1.f + __expf(-x)); }
static __device__ __forceinline__ bf16x8 asbf(f32x4 v) {
  union { f32x4 f; bf16x8 b; } u; u.f = v; return u.b;
}
// Raw barrier: LDS-visibility only; global loads/stores stay in flight.
static __device__ __forceinline__ void wg_barrier() {
  asm volatile("s_waitcnt lgkmcnt(0)" ::: "memory");
  __builtin_amdgcn_s_barrier();
  __builtin_amdgcn_sched_barrier(0);
}

// ---- generic f32 -> bf16 (n4 float4 groups) ----
__global__ __launch_bounds__(256) void cvt_bf16(
    const float* __restrict__ s, bf16* __restrict__ d, int n4)
{
  int i = blockIdx.x * 256 + threadIdx.x;
  if (i < n4) {
    float4 v = ((const float4*)s)[i];
    bf16x4 o;
    o[0] = (bf16)v.x; o[1] = (bf16)v.y; o[2] = (bf16)v.z; o[3] = (bf16)v.w;
    ((bf16x4*)d)[i] = o;
  }
}

// ---- one-shot weight conversion: 12 GRU mats (196608 ea) + linW (131072) ----
__global__ __launch_bounds__(256) void conv13(
    const float* s0, const float* s1, const float* s2, const float* s3,
    const float* s4, const float* s5, const float* s6, const float* s7,
    const float* s8, const float* s9, const float* s10, const float* s11,
    const float* s12, bf16* __restrict__ dst)
{
  const float* srcs[13] = {s0,s1,s2,s3,s4,s5,s6,s7,s8,s9,s10,s11,s12};
  int m = blockIdx.y;
  int n4 = (m == 12) ? 32768 : 49152;
  int i = blockIdx.x * 256 + threadIdx.x;
  if (i >= n4) return;
  float4 v = ((const float4*)srcs[m])[i];
  bf16x4 o;
  o[0] = (bf16)v.x; o[1] = (bf16)v.y; o[2] = (bf16)v.z; o[3] = (bf16)v.w;
  ((bf16x4*)(dst + (size_t)m * 196608))[i] = o;
}

// ---------------------------------------------------------------------------
// xw = X(M x 256) @ W(768 x 256)^T + bias -> (M x 768) bf16.
// Wave handles 64 rows x 16 cols (weight frags reused 4x). grid.x=(M/64)*12.
// gridDim.y selects (W0,b0,o0)/(W1,b1,o1).
// ---------------------------------------------------------------------------
__global__ __launch_bounds__(256) void xw_gemm(
    const bf16* __restrict__ X,
    const bf16* __restrict__ W0, const float* __restrict__ b0, bf16* __restrict__ o0,
    const bf16* __restrict__ W1, const float* __restrict__ b1, bf16* __restrict__ o1)
{
  const bf16* W = blockIdx.y ? W1 : W0;
  const float* bias = blockIdx.y ? b1 : b0;
  bf16* out = blockIdx.y ? o1 : o0;
  int wave = (int)blockIdx.x * 4 + (threadIdx.x >> 6);
  int g64 = wave / 48, ct = wave - g64 * 48;
  int lane = threadIdx.x & 63;
  int r16 = lane & 15, g4 = lane >> 4;
  const bf16* wp = W + (size_t)(ct * 16 + r16) * 256;
  const bf16* xb = X + ((size_t)g64 * 64 + r16) * 256;
  f32x4 a0 = {0,0,0,0}, a1 = {0,0,0,0}, a2 = {0,0,0,0}, a3 = {0,0,0,0};
#pragma unroll
  for (int kk = 0; kk < 8; kk++) {
    int k0 = kk * 32 + g4 * 8;
    bf16x8 wf = *(const bf16x8*)(wp + k0);
    a0 = mfma16(*(const bf16x8*)(xb + k0), wf, a0);
    a1 = mfma16(*(const bf16x8*)(xb + 4096 + k0), wf, a1);
    a2 = mfma16(*(const bf16x8*)(xb + 8192 + k0), wf, a2);
    a3 = mfma16(*(const bf16x8*)(xb + 12288 + k0), wf, a3);
  }
  float bv = bias[ct * 16 + r16];
#pragma unroll
  for (int rt = 0; rt < 4; rt++) {
    f32x4 ac = rt == 0 ? a0 : rt == 1 ? a1 : rt == 2 ? a2 : a3;
#pragma unroll
    for (int j = 0; j < 4; j++)
      out[(size_t)(g64 * 64 + rt * 16 + g4 * 4 + j) * 768 + ct * 16 + r16] = (bf16)(ac[j] + bv);
  }
}

// ---------------------------------------------------------------------------
// xw1 = emb[tok] @ W^T + bias (gather fused). blockIdx.y = t.
// grid.x = (c/64)*12. out row = t*c + n.
// ---------------------------------------------------------------------------
__global__ __launch_bounds__(256) void xw_gather_gemm(
    const int* __restrict__ tok, const bf16* __restrict__ embb,
    const bf16* __restrict__ W, const float* __restrict__ bias,
    bf16* __restrict__ out, int c)
{
  int t = blockIdx.y;
  int wave = (int)blockIdx.x * 4 + (threadIdx.x >> 6);
  int g64 = wave / 48, ct = wave - g64 * 48;
  int lane = threadIdx.x & 63;
  int r16 = lane & 15, g4 = lane >> 4;
  const bf16* wp = W + (size_t)(ct * 16 + r16) * 256;
  const bf16* ap[4];
#pragma unroll
  for (int rt = 0; rt < 4; rt++) {
    int n = g64 * 64 + rt * 16 + r16;
    int tk = tok[((n >> 5) << 10) + (t << 5) + (n & 31)];
    ap[rt] = embb + (size_t)tk * 256;
  }
  f32x4 a0 = {0,0,0,0}, a1 = {0,0,0,0}, a2 = {0,0,0,0}, a3 = {0,0,0,0};
#pragma unroll
  for (int kk = 0; kk < 8; kk++) {
    int k0 = kk * 32 + g4 * 8;
    bf16x8 wf = *(const bf16x8*)(wp + k0);
    a0 = mfma16(*(const bf16x8*)(ap[0] + k0), wf, a0);
    a1 = mfma16(*(const bf16x8*)(ap[1] + k0), wf, a1);
    a2 = mfma16(*(const bf16x8*)(ap[2] + k0), wf, a2);
    a3 = mfma16(*(const bf16x8*)(ap[3] + k0), wf, a3);
  }
  float bv = bias[ct * 16 + r16];
#pragma unroll
  for (int rt = 0; rt < 4; rt++) {
    f32x4 ac = rt == 0 ? a0 : rt == 1 ? a1 : rt == 2 ? a2 : a3;
#pragma unroll
    for (int j = 0; j < 4; j++)
      out[((size_t)t * c + g64 * 64 + rt * 16 + g4 * 4 + j) * 768 + ct * 16 + r16] = (bf16)(ac[j] + bv);
  }
}

// ---------------------------------------------------------------------------
// Persistent GRU v4. 512 thr = 8 waves; wave w owns 32 cols. Wh pinned in
// VGPRs (48 f32x4 = 192 VGPR); amdgpu_waves_per_eu(1,2) raises the VGPR
// budget to 512 so the pin cannot spill. 16 batch rows per WG in LDS.
// xw staged to LDS dbuf, prefetched 1 step ahead; raw barriers keep global
// ops in flight. rev: traverse steps in reverse. lng: fuse LN(256) on output.
// ---------------------------------------------------------------------------
__global__ __launch_bounds__(512)
__attribute__((amdgpu_waves_per_eu(1, 2)))
void pgru(
    const bf16* __restrict__ xw0, const bf16* __restrict__ Wh0, const float* __restrict__ bh0,
    const bf16* __restrict__ xw1, const bf16* __restrict__ Wh1, const float* __restrict__ bh1,
    bf16* __restrict__ yout0, bf16* __restrict__ yout1, int ostride,
    const float* __restrict__ lng, const float* __restrict__ lnb,
    int steps, int Mtot, int rev0, int rev1)
{
  int dir = blockIdx.y;
  const bf16*  xw = dir ? xw1 : xw0;
  const bf16*  Wh = dir ? Wh1 : Wh0;
  const float* bh = dir ? bh1 : bh0;
  bf16* yout = dir ? yout1 : yout0;
  int rev = dir ? rev1 : rev0;

  __shared__ __align__(16) bf16 hbuf[16][264];
  __shared__ __align__(16) bf16 xbuf[2][16][776];

  int tid = threadIdx.x;
  int w = tid >> 6, lane = tid & 63, r16 = lane & 15, g4 = lane >> 4;
  int rowbase = (int)blockIdx.x * 16;
  int c0 = w * 32 + r16, c1 = w * 32 + 16 + r16;

  for (int i2 = tid; i2 < 528; i2 += 512) ((bf16x8*)hbuf)[i2] = (bf16x8){};

  // Wh -> registers, pinned so the compiler cannot rematerialize from L2
  f32x4 wr0[8], wz0[8], wn0[8], wr1[8], wz1[8], wn1[8];
  {
    const bf16* W0 = Wh + (size_t)c0 * 256;
    const bf16* W1 = Wh + (size_t)c1 * 256;
#pragma unroll
    for (int kk = 0; kk < 8; kk++) {
      int k0 = kk * 32 + g4 * 8;
      wr0[kk] = *(const f32x4*)(W0 + k0);          asm volatile("" : "+v"(wr0[kk]));
      wz0[kk] = *(const f32x4*)(W0 + 65536 + k0);  asm volatile("" : "+v"(wz0[kk]));
      wn0[kk] = *(const f32x4*)(W0 + 131072 + k0); asm volatile("" : "+v"(wn0[kk]));
      wr1[kk] = *(const f32x4*)(W1 + k0);          asm volatile("" : "+v"(wr1[kk]));
      wz1[kk] = *(const f32x4*)(W1 + 65536 + k0);  asm volatile("" : "+v"(wz1[kk]));
      wn1[kk] = *(const f32x4*)(W1 + 131072 + k0); asm volatile("" : "+v"(wn1[kk]));
    }
  }
  float bhr0 = bh[c0], bhz0 = bh[c0 + 256], bhn0 = bh[c0 + 512];
  float bhr1 = bh[c1], bhz1 = bh[c1 + 256], bhn1 = bh[c1 + 512];

  // stage step 0 into xbuf[0]
  {
    int st0 = rev ? steps - 1 : 0;
    const bf16* src = xw + ((size_t)st0 * Mtot + rowbase) * 768;
#pragma unroll
    for (int it = 0; it < 3; it++) {
      int idx = it * 4096 + tid * 8;
      f32x4 v = *(const f32x4*)(src + idx);
      int m = idx / 768, k = idx - m * 768;
      *(f32x4*)&xbuf[0][m][k] = v;
    }
  }
  wg_barrier();

  for (int i = 0; i < steps; i++) {
    int cur = i & 1;
    int st = rev ? steps - 1 - i : i;
    // prefetch next step's xw tile (in flight across the barriers)
    f32x4 pf0 = {}, pf1 = {}, pf2 = {};
    bool havepf = (i + 1 < steps);
    if (havepf) {
      int stn = rev ? steps - 2 - i : i + 1;
      const bf16* src = xw + ((size_t)stn * Mtot + rowbase) * 768;
      pf0 = *(const f32x4*)(src + tid * 8);
      pf1 = *(const f32x4*)(src + 4096 + tid * 8);
      pf2 = *(const f32x4*)(src + 8192 + tid * 8);
    }
    // h @ Wh : LDS A-frags x register weights
    f32x4 ar0 = {0,0,0,0}, az0 = {0,0,0,0}, an0 = {0,0,0,0};
    f32x4 ar1 = {0,0,0,0}, az1 = {0,0,0,0}, an1 = {0,0,0,0};
#pragma unroll
    for (int kk = 0; kk < 8; kk++) {
      bf16x8 a = *(const bf16x8*)&hbuf[r16][kk * 32 + g4 * 8];
      ar0 = mfma16(a, asbf(wr0[kk]), ar0);
      az0 = mfma16(a, asbf(wz0[kk]), az0);
      an0 = mfma16(a, asbf(wn0[kk]), an0);
      ar1 = mfma16(a, asbf(wr1[kk]), ar1);
      az1 = mfma16(a, asbf(wz1[kk]), az1);
      an1 = mfma16(a, asbf(wn1[kk]), an1);
    }
    // gates
    float hn0[4], hn1[4];
#pragma unroll
    for (int j = 0; j < 4; j++) {
      int m = g4 * 4 + j;
      const bf16* xq = &xbuf[cur][m][0];
      {
        float r = sigm((float)xq[c0] + ar0[j] + bhr0);
        float z = sigm((float)xq[c0 + 256] + az0[j] + bhz0);
        float n = tanhf((float)xq[c0 + 512] + r * (an0[j] + bhn0));
        hn0[j] = (1.f - z) * n + z * (float)hbuf[m][c0];
      }
      {
        float r = sigm((float)xq[c1] + ar1[j] + bhr1);
        float z = sigm((float)xq[c1 + 256] + az1[j] + bhz1);
        float n = tanhf((float)xq[c1 + 512] + r * (an1[j] + bhn1));
        hn1[j] = (1.f - z) * n + z * (float)hbuf[m][c1];
      }
    }
    wg_barrier();                    // all hbuf/xbuf[cur] reads done
    // commit h_{i+1}
#pragma unroll
    for (int j = 0; j < 4; j++) {
      int m = g4 * 4 + j;
      hbuf[m][c0] = (bf16)hn0[j];
      hbuf[m][c1] = (bf16)hn1[j];
    }
    // stage prefetched tile (vmcnt waits are fine-grained on pf regs)
    if (havepf) {
      { int idx = tid * 8;        int m = idx / 768, k = idx - m * 768; *(f32x4*)&xbuf[cur ^ 1][m][k] = pf0; }
      { int idx = 4096 + tid * 8; int m = idx / 768, k = idx - m * 768; *(f32x4*)&xbuf[cur ^ 1][m][k] = pf1; }
      { int idx = 8192 + tid * 8; int m = idx / 768, k = idx - m * 768; *(f32x4*)&xbuf[cur ^ 1][m][k] = pf2; }
    }
    if (!lng) {
#pragma unroll
      for (int j = 0; j < 4; j++) {
        size_t ro = ((size_t)st * Mtot + rowbase + g4 * 4 + j) * ostride;
        yout[ro + c0] = (bf16)hn0[j];
        yout[ro + c1] = (bf16)hn1[j];
      }
    }
    wg_barrier();                    // h_{i+1} + next xbuf visible
    if (lng) {
      // fused LN(256); recurrence keeps raw h. wave -> rows 2w, 2w+1
#pragma unroll
      for (int rr = 0; rr < 2; rr++) {
        int r = w * 2 + rr;
        bf16x4 v4 = *(const bf16x4*)&hbuf[r][lane * 4];
        float v[4]; float sm = 0.f, sq = 0.f;
#pragma unroll
        for (int j = 0; j < 4; j++) { v[j] = (float)v4[j]; sm += v[j]; sq += v[j] * v[j]; }
        for (int msk = 32; msk; msk >>= 1) { sm += __shfl_xor(sm, msk); sq += __shfl_xor(sq, msk); }
        float mu  = sm * (1.f / 256.f);
        float var = sq * (1.f / 256.f) - mu * mu;
        float inv = rsqrtf(fmaxf(var, 0.f) + 1e-5f);
        bf16x4 o;
#pragma unroll
        for (int j = 0; j < 4; j++)
          o[j] = (bf16)((v[j] - mu) * inv * lng[lane * 4 + j] + lnb[lane * 4 + j]);
        *(bf16x4*)&yout[((size_t)st * Mtot + rowbase + r) * ostride + lane * 4] = o;
      }
    }
  }
}

// ---------------------------------------------------------------------------
// Sentence tail, t-parallel: block (r-tile, tg) accumulates 4 t's of
// tanh(LN512(hf||hb) @ linW^T + b) into part[tg] (f32). grid (c/16, 8).
// ---------------------------------------------------------------------------
__global__ __launch_bounds__(256) void sent_tail_part(
    const bf16* __restrict__ hf, const bf16* __restrict__ hb,
    const float* __restrict__ gam, const float* __restrict__ bet,
    const bf16* __restrict__ W, const float* __restrict__ bias,
    float* __restrict__ part, int c)
{
  int wave = threadIdx.x >> 6;
  int lane = threadIdx.x & 63;
  int r16 = lane & 15, g4 = lane >> 4;
  int r0 = (int)blockIdx.x << 4;
  int tg = blockIdx.y;
  size_t rowoff = (size_t)(r0 + r16) * 256;

  f32x4 ms0 = {0,0,0,0}, ms1 = {0,0,0,0}, ms2 = {0,0,0,0}, ms3 = {0,0,0,0};

  for (int tt = 0; tt < 4; tt++) {
    int t = tg * 4 + tt;
    const bf16* pf = hf + (size_t)t * c * 256 + rowoff;
    const bf16* pb = hb + (size_t)t * c * 256 + rowoff;
    bf16x8 xv[16];
    float s = 0.f, sq = 0.f;
#pragma unroll
    for (int kk = 0; kk < 16; kk++) {
      int k0 = kk * 32 + g4 * 8;
      xv[kk] = (kk < 8) ? *(const bf16x8*)(pf + k0) : *(const bf16x8*)(pb + k0 - 256);
#pragma unroll
      for (int j = 0; j < 8; j++) { float f = (float)xv[kk][j]; s += f; sq += f * f; }
    }
    s  += __shfl_xor(s, 16);  s  += __shfl_xor(s, 32);
    sq += __shfl_xor(sq, 16); sq += __shfl_xor(sq, 32);
    float mu  = s * (1.f / 512.f);
    float var = sq * (1.f / 512.f) - mu * mu;
    float inv = rsqrtf(fmaxf(var, 0.f) + 1e-5f);
#pragma unroll
    for (int kk = 0; kk < 16; kk++) {
      int k0 = kk * 32 + g4 * 8;
      float ga[8], be[8];
      *(float4*)(ga)     = *(const float4*)(gam + k0);
      *(float4*)(ga + 4) = *(const float4*)(gam + k0 + 4);
      *(float4*)(be)     = *(const float4*)(bet + k0);
      *(float4*)(be + 4) = *(const float4*)(bet + k0 + 4);
#pragma unroll
      for (int j = 0; j < 8; j++)
        xv[kk][j] = (bf16)(((float)xv[kk][j] - mu) * inv * ga[j] + be[j]);
    }
#pragma unroll
    for (int tc = 0; tc < 4; tc++) {
      int cj = wave * 64 + tc * 16;
      const bf16* wp = W + (size_t)(cj + r16) * 512;
      f32x4 acc = {0,0,0,0};
#pragma unroll
      for (int kk = 0; kk < 16; kk++)
        acc = mfma16(xv[kk], *(const bf16x8*)(wp + kk * 32 + g4 * 8), acc);
      float bb = bias[cj + r16];
      f32x4* msp = (tc == 0) ? &ms0 : (tc == 1) ? &ms1 : (tc == 2) ? &ms2 : &ms3;
#pragma unroll
      for (int j = 0; j < 4; j++) (*msp)[j] += tanhf(acc[j] + bb);
    }
  }
#pragma unroll
  for (int tc = 0; tc < 4; tc++) {
    int cj = wave * 64 + tc * 16;
    f32x4 ms = (tc == 0) ? ms0 : (tc == 1) ? ms1 : (tc == 2) ? ms2 : ms3;
#pragma unroll
    for (int j = 0; j < 4; j++)
      part[((size_t)tg * c + r0 + g4 * 4 + j) * 256 + cj + r16] = ms[j];
  }
}

// sum 8 partials, scale 1/32, write bf16. grid = c blocks x 256 thr.
__global__ __launch_bounds__(256) void tail_reduce(
    const float* __restrict__ part, bf16* __restrict__ out, int c)
{
  int idx = blockIdx.x * 256 + threadIdx.x;
  float s = 0.f;
#pragma unroll
  for (int g = 0; g < 8; g++) s += part[(size_t)g * c * 256 + idx];
  out[idx] = (bf16)(s * 0.03125f);
}

// ---------------------------------------------------------------------------
// Fused LN(512) + sigmoid head: out(3072x2 f32). Wave per row.
// ---------------------------------------------------------------------------
__global__ __launch_bounds__(256) void ln_out_head(
    const bf16* __restrict__ X, const float* __restrict__ lng, const float* __restrict__ lnb,
    const float* __restrict__ W, const float* __restrict__ bias, float* __restrict__ out)
{
  int w = threadIdx.x >> 6, lane = threadIdx.x & 63;
  int row = (int)blockIdx.x * 4 + w;
  bf16x8 v8 = *(const bf16x8*)&X[(size_t)row * 512 + lane * 8];
  float v[8]; float sm = 0.f, sq = 0.f;
#pragma unroll
  for (int j = 0; j < 8; j++) { v[j] = (float)v8[j]; sm += v[j]; sq += v[j] * v[j]; }
  for (int msk = 32; msk; msk >>= 1) { sm += __shfl_xor(sm, msk); sq += __shfl_xor(sq, msk); }
  float mu  = sm * (1.f / 512.f);
  float var = sq * (1.f / 512.f) - mu * mu;
  float inv = rsqrtf(fmaxf(var, 0.f) + 1e-5f);
  float a0 = 0.f, a1 = 0.f;
  int base = lane * 8;
#pragma unroll
  for (int j = 0; j < 8; j++) {
    float y = (v[j] - mu) * inv * lng[base + j] + lnb[base + j];
    a0 += y * W[base + j];
    a1 += y * W[512 + base + j];
  }
  for (int msk = 32; msk; msk >>= 1) { a0 += __shfl_xor(a0, msk); a1 += __shfl_xor(a1, msk); }
  if (lane == 0) {
    out[(size_t)row * 2 + 0] = sigm(a0 + bias[0]);
    out[(size_t)row * 2 + 1] = sigm(a1 + bias[1]);
  }
}

// ---------------------------------------------------------------------------
extern "C" void kernel_launch(void* const* d_in, const int* in_sizes, int n_in,
                              void* d_out, int out_size, void* d_ws, size_t ws_size,
                              hipStream_t stream)
{
  (void)in_sizes; (void)n_in; (void)out_size;
  const int*   tokens = (const int*)d_in[0];
  const float* emb    = (const float*)d_in[1];
  auto fp = [&](int i) { return (const float*)d_in[i]; };
  const float *s_WiF = fp(2),  *s_WhF = fp(3),  *s_biF = fp(4),  *s_bhF = fp(5);
  const float *s_lnF_g = fp(6), *s_lnF_b = fp(7);
  const float *s_Wi_f = fp(8),  *s_Wh_f = fp(9),  *s_bi_f = fp(10), *s_bh_f = fp(11);
  const float *s_Wi_b = fp(12), *s_Wh_b = fp(13), *s_bi_b = fp(14), *s_bh_b = fp(15);
  const float *s_ln_g = fp(16), *s_ln_b = fp(17), *s_linW = fp(18), *s_linb = fp(19);
  const float *dWiF = fp(20), *dWhF = fp(21), *dbiF = fp(22), *dbhF = fp(23);
  const float *d_lnF_g = fp(24), *d_lnF_b = fp(25);
  const float *dWi_f = fp(26), *dWh_f = fp(27), *dbi_f = fp(28), *dbh_f = fp(29);
  const float *dWi_b = fp(30), *dWh_b = fp(31), *dbi_b = fp(32), *dbh_b = fp(33);
  const float *d_ln_g = fp(34), *d_ln_b = fp(35), *out_W = fp(36), *out_b = fp(37);

  const int T = 32, S = 96;
  const int GW = 196608;

  // ---- converted bf16 weights + emb ----
  bf16* wc = (bf16*)d_ws;
  bf16 *c_sWiF = wc,         *c_sWhF = wc + GW;
  bf16 *c_sWif = wc + 2*GW,  *c_sWhf = wc + 3*GW;
  bf16 *c_sWib = wc + 4*GW,  *c_sWhb = wc + 5*GW;
  bf16 *c_dWiF = wc + 6*GW,  *c_dWhF = wc + 7*GW;
  bf16 *c_dWif = wc + 8*GW,  *c_dWhf = wc + 9*GW;
  bf16 *c_dWib = wc + 10*GW, *c_dWhb = wc + 11*GW;
  bf16 *c_linW = wc + 12*GW;
  const size_t WB = (size_t)(12 * GW + 131072) * 2;       // 4,980,736
  bf16* embb = (bf16*)((char*)d_ws + WB);                 // 32000x256 bf16
  const size_t EB = (size_t)32000 * 256 * 2;              // 16,384,000

  conv13<<<dim3(192, 13), 256, 0, stream>>>(
      s_WiF, s_WhF, s_Wi_f, s_Wh_f, s_Wi_b, s_Wh_b,
      dWiF, dWhF, dWi_f, dWh_f, dWi_b, dWh_b, s_linW, wc);
  cvt_bf16<<<8000, 256, 0, stream>>>(emb, embb, 2048000);

  // ---- fixed doc-side buffers ----
  char* ws = (char*)d_ws + WB + EB;
  bf16* store = (bf16*)ws;                           // (3072, 256)
  bf16* yd1ln = store + (size_t)3072 * 256;          // (3072, 256)
  bf16* ybid  = yd1ln + (size_t)3072 * 256;          // (3072, 512)
  bf16* xw_u  = ybid  + (size_t)3072 * 512;          // (3072, 768)
  bf16* xwdf  = xw_u  + (size_t)3072 * 768;
  bf16* xwdb  = xwdf  + (size_t)3072 * 768;
  const size_t fixedB = WB + EB
      + ((size_t)3072 * 256 * 2 + (size_t)3072 * 512 + (size_t)3 * 3072 * 768) * 2;

  // ---- sentence chunk size (rows; multiple of 64) ----
  // per-row: xw 49152 + y1ln 16384 + hf 16384 + hb 16384 = 98304 B
  int c = 3072;
  while (c > 192 && fixedB + (size_t)98304 * c > ws_size) c >>= 1;
  char* cb = (char*)d_ws + fixedB;
  bf16*  xw   = (bf16*)cb;                           // (T*c, 768), reused 3x
  bf16*  y1ln = (bf16*)(cb + (size_t)49152 * c);     // (T*c, 256)
  bf16*  hf   = (bf16*)(cb + (size_t)65536 * c);     // (T*c, 256)
  bf16*  hb   = (bf16*)(cb + (size_t)81920 * c);     // (T*c, 256)
  float* part = (float*)cb;                          // (8, c, 256) f32, alias xw

  // ---- sentence encoder, chunked ----
  for (int base = 0; base < 3072; base += c) {
    const int* tkb = tokens + (size_t)base * 32;
    xw_gather_gemm<<<dim3((c / 64) * 12, T), 256, 0, stream>>>(
        tkb, embb, c_sWiF, s_biF, xw, c);
    pgru<<<dim3(c / 16, 1), 512, 0, stream>>>(
        xw, c_sWhF, s_bhF, nullptr, nullptr, nullptr,
        y1ln, nullptr, 256, s_lnF_g, s_lnF_b, T, c, 0, 0);
    xw_gemm<<<dim3((T * c / 64) * 12, 1), 256, 0, stream>>>(
        y1ln, c_sWif, s_bi_f, xw, nullptr, nullptr, nullptr);
    pgru<<<dim3(c / 16, 1), 512, 0, stream>>>(
        xw, c_sWhf, s_bh_f, nullptr, nullptr, nullptr,
        hf, nullptr, 256, nullptr, nullptr, T, c, 0, 0);
    xw_gemm<<<dim3((T * c / 64) * 12, 1), 256, 0, stream>>>(
        y1ln, c_sWib, s_bi_b, xw, nullptr, nullptr, nullptr);
    pgru<<<dim3(c / 16, 1), 512, 0, stream>>>(
        xw, c_sWhb, s_bh_b, nullptr, nullptr, nullptr,
        hb, nullptr, 256, nullptr, nullptr, T, c, 1, 0);
    sent_tail_part<<<dim3(c / 16, 8), 256, 0, stream>>>(
        hf, hb, s_ln_g, s_ln_b, c_linW, s_linb, part, c);
    tail_reduce<<<c, 256, 0, stream>>>(part, store + (size_t)base * 256, c);
  }

  // ---- document encoder ----
  xw_gemm<<<dim3((3072 / 64) * 12, 1), 256, 0, stream>>>(
      store, c_dWiF, dbiF, xw_u, nullptr, nullptr, nullptr);
  pgru<<<dim3(2, 1), 512, 0, stream>>>(
      xw_u, c_dWhF, dbhF, nullptr, nullptr, nullptr,
      yd1ln, nullptr, 256, d_lnF_g, d_lnF_b, S, 32, 0, 0);
  xw_gemm<<<dim3((3072 / 64) * 12, 2), 256, 0, stream>>>(
      yd1ln, c_dWif, dbi_f, xwdf, c_dWib, dbi_b, xwdb);
  pgru<<<dim3(2, 2), 512, 0, stream>>>(
      xwdf, c_dWhf, dbh_f, xwdb, c_dWhb, dbh_b,
      ybid, ybid + 256, 512, nullptr, nullptr, S, 32, 0, 1);
  ln_out_head<<<768, 256, 0, stream>>>(ybid, d_ln_g, d_ln_b, out_W, out_b,
                                       (float*)d_out);
}

// Round 9
// 3635.181 us; speedup vs baseline: 1.0646x; 1.0646x over previous
//
#include <hip/hip_runtime.h>

// ---------------------------------------------------------------------------
// SequenceTaggle: hierarchical GRU (sentence enc -> doc enc) on MI355X.
// V=32000 E=256 H=256 O=2 S=96 T=32 B=32, N = S*B = 3072.
// DEVICE DTYPES: float tensors f32; tokens int32; output f32.
// Internal: bf16 MFMA, f32 accumulation.
// pgru v5: weights register-resident. LDS padded >80KB so only 1 WG/CU fits
// -> LLVM raises the per-wave VGPR budget to 256 (2 waves/SIMD) -> no spill.
// xw staged via global_load_lds into per-wave self-regions; counted vmcnt.
// bh_r/bh_z folded into the xw GEMM bias (prep_bias); only bhn in pgru.
// ---------------------------------------------------------------------------

typedef __bf16 bf16;
typedef __bf16 bf16x8 __attribute__((ext_vector_type(8)));
typedef __bf16 bf16x4 __attribute__((ext_vector_type(4)));
typedef float  f32x4  __attribute__((ext_vector_type(4)));

static __device__ __forceinline__ f32x4 mfma16(bf16x8 a, bf16x8 b, f32x4 c) {
  // A: lane row = lane&15, k = (lane>>4)*8 + j ; B: lane col = lane&15, same k
  // D: col = lane&15, row = (lane>>4)*4 + reg
  return __builtin_amdgcn_mfma_f32_16x16x32_bf16(a, b, c, 0, 0, 0);
}
static __device__ __forceinline__ float sigm(float x) { return 1.f / (1.f + __expf(-x)); }
static __device__ __forceinline__ bf16x8 asbf(f32x4 v) {
  union { f32x4 f; bf16x8 b; } u; u.f = v; return u.b;
}
// Raw barrier: LDS-visibility only; global loads/stores stay in flight.
static __device__ __forceinline__ void wg_barrier() {
  asm volatile("s_waitcnt lgkmcnt(0)" ::: "memory");
  __builtin_amdgcn_s_barrier();
  __builtin_amdgcn_sched_barrier(0);
}
// 16B global -> LDS DMA (LDS dest wave-uniform base + lane*16)
static __device__ __forceinline__ void gload16(const bf16* g, bf16* l) {
  __builtin_amdgcn_global_load_lds(
      (const __attribute__((address_space(1))) void*)g,
      (__attribute__((address_space(3))) void*)l, 16, 0, 0);
}

// ---- generic f32 -> bf16 (n4 float4 groups) ----
__global__ __launch_bounds__(256) void cvt_bf16(
    const float* __restrict__ s, bf16* __restrict__ d, int n4)
{
  int i = blockIdx.x * 256 + threadIdx.x;
  if (i < n4) {
    float4 v = ((const float4*)s)[i];
    bf16x4 o;
    o[0] = (bf16)v.x; o[1] = (bf16)v.y; o[2] = (bf16)v.z; o[3] = (bf16)v.w;
    ((bf16x4*)d)[i] = o;
  }
}

// ---- one-shot weight conversion: 12 GRU mats (196608 ea) + linW (131072) ----
__global__ __launch_bounds__(256) void conv13(
    const float* s0, const float* s1, const float* s2, const float* s3,
    const float* s4, const float* s5, const float* s6, const float* s7,
    const float* s8, const float* s9, const float* s10, const float* s11,
    const float* s12, bf16* __restrict__ dst)
{
  const float* srcs[13] = {s0,s1,s2,s3,s4,s5,s6,s7,s8,s9,s10,s11,s12};
  int m = blockIdx.y;
  int n4 = (m == 12) ? 32768 : 49152;
  int i = blockIdx.x * 256 + threadIdx.x;
  if (i >= n4) return;
  float4 v = ((const float4*)srcs[m])[i];
  bf16x4 o;
  o[0] = (bf16)v.x; o[1] = (bf16)v.y; o[2] = (bf16)v.z; o[3] = (bf16)v.w;
  ((bf16x4*)(dst + (size_t)m * 196608))[i] = o;
}

// ---- bmod[g][i] = bi[i] + (i<512 ? bh[i] : 0)  for 6 GRUs. grid (3,6). ----
__global__ __launch_bounds__(256) void prep_bias(
    const float* b0i, const float* b0h, const float* b1i, const float* b1h,
    const float* b2i, const float* b2h, const float* b3i, const float* b3h,
    const float* b4i, const float* b4h, const float* b5i, const float* b5h,
    float* __restrict__ out)
{
  const float* bis[6] = {b0i,b1i,b2i,b3i,b4i,b5i};
  const float* bhs[6] = {b0h,b1h,b2h,b3h,b4h,b5h};
  int g = blockIdx.y;
  int i = blockIdx.x * 256 + threadIdx.x;
  if (i < 768)
    out[g * 768 + i] = bis[g][i] + (i < 512 ? bhs[g][i] : 0.f);
}

// ---------------------------------------------------------------------------
// xw = X(M x 256) @ W(768 x 256)^T + bias -> (M x 768) bf16.
// Wave handles 64 rows x 16 cols (weight frags reused 4x). grid.x=(M/64)*12.
// gridDim.y selects (W0,b0,o0)/(W1,b1,o1).
// ---------------------------------------------------------------------------
__global__ __launch_bounds__(256) void xw_gemm(
    const bf16* __restrict__ X,
    const bf16* __restrict__ W0, const float* __restrict__ b0, bf16* __restrict__ o0,
    const bf16* __restrict__ W1, const float* __restrict__ b1, bf16* __restrict__ o1)
{
  const bf16* W = blockIdx.y ? W1 : W0;
  const float* bias = blockIdx.y ? b1 : b0;
  bf16* out = blockIdx.y ? o1 : o0;
  int wave = (int)blockIdx.x * 4 + (threadIdx.x >> 6);
  int g64 = wave / 48, ct = wave - g64 * 48;
  int lane = threadIdx.x & 63;
  int r16 = lane & 15, g4 = lane >> 4;
  const bf16* wp = W + (size_t)(ct * 16 + r16) * 256;
  const bf16* xb = X + ((size_t)g64 * 64 + r16) * 256;
  f32x4 a0 = {0,0,0,0}, a1 = {0,0,0,0}, a2 = {0,0,0,0}, a3 = {0,0,0,0};
#pragma unroll
  for (int kk = 0; kk < 8; kk++) {
    int k0 = kk * 32 + g4 * 8;
    bf16x8 wf = *(const bf16x8*)(wp + k0);
    a0 = mfma16(*(const bf16x8*)(xb + k0), wf, a0);
    a1 = mfma16(*(const bf16x8*)(xb + 4096 + k0), wf, a1);
    a2 = mfma16(*(const bf16x8*)(xb + 8192 + k0), wf, a2);
    a3 = mfma16(*(const bf16x8*)(xb + 12288 + k0), wf, a3);
  }
  float bv = bias[ct * 16 + r16];
#pragma unroll
  for (int rt = 0; rt < 4; rt++) {
    f32x4 ac = rt == 0 ? a0 : rt == 1 ? a1 : rt == 2 ? a2 : a3;
#pragma unroll
    for (int j = 0; j < 4; j++)
      out[(size_t)(g64 * 64 + rt * 16 + g4 * 4 + j) * 768 + ct * 16 + r16] = (bf16)(ac[j] + bv);
  }
}

// ---------------------------------------------------------------------------
// xw1 = emb[tok] @ W^T + bias (gather fused). blockIdx.y = t.
// grid.x = (c/64)*12. out row = t*c + n.
// ---------------------------------------------------------------------------
__global__ __launch_bounds__(256) void xw_gather_gemm(
    const int* __restrict__ tok, const bf16* __restrict__ embb,
    const bf16* __restrict__ W, const float* __restrict__ bias,
    bf16* __restrict__ out, int c)
{
  int t = blockIdx.y;
  int wave = (int)blockIdx.x * 4 + (threadIdx.x >> 6);
  int g64 = wave / 48, ct = wave - g64 * 48;
  int lane = threadIdx.x & 63;
  int r16 = lane & 15, g4 = lane >> 4;
  const bf16* wp = W + (size_t)(ct * 16 + r16) * 256;
  const bf16* ap[4];
#pragma unroll
  for (int rt = 0; rt < 4; rt++) {
    int n = g64 * 64 + rt * 16 + r16;
    int tk = tok[((n >> 5) << 10) + (t << 5) + (n & 31)];
    ap[rt] = embb + (size_t)tk * 256;
  }
  f32x4 a0 = {0,0,0,0}, a1 = {0,0,0,0}, a2 = {0,0,0,0}, a3 = {0,0,0,0};
#pragma unroll
  for (int kk = 0; kk < 8; kk++) {
    int k0 = kk * 32 + g4 * 8;
    bf16x8 wf = *(const bf16x8*)(wp + k0);
    a0 = mfma16(*(const bf16x8*)(ap[0] + k0), wf, a0);
    a1 = mfma16(*(const bf16x8*)(ap[1] + k0), wf, a1);
    a2 = mfma16(*(const bf16x8*)(ap[2] + k0), wf, a2);
    a3 = mfma16(*(const bf16x8*)(ap[3] + k0), wf, a3);
  }
  float bv = bias[ct * 16 + r16];
#pragma unroll
  for (int rt = 0; rt < 4; rt++) {
    f32x4 ac = rt == 0 ? a0 : rt == 1 ? a1 : rt == 2 ? a2 : a3;
#pragma unroll
    for (int j = 0; j < 4; j++)
      out[((size_t)t * c + g64 * 64 + rt * 16 + g4 * 4 + j) * 768 + ct * 16 + r16] = (bf16)(ac[j] + bv);
  }
}

// ---------------------------------------------------------------------------
// Persistent GRU v5. 512 thr = 8 waves; wave w owns 32 cols (2 tiles,
// sequential accumulators). Wh pinned in VGPRs (192). LDS padded >80KB so
// only 1 WG/CU fits -> VGPR budget 256 -> no spill. xw staged via
// global_load_lds into per-wave self-regions xbuf[b][w][gate][16][32];
// counted vmcnt(3) (never 0 mid-loop). bh_r/bh_z pre-folded into xw.
// ---------------------------------------------------------------------------
__global__ __launch_bounds__(512)
__attribute__((amdgpu_waves_per_eu(1, 2)))
void pgru(
    const bf16* __restrict__ xw0, const bf16* __restrict__ Wh0, const float* __restrict__ bh0,
    const bf16* __restrict__ xw1, const bf16* __restrict__ Wh1, const float* __restrict__ bh1,
    bf16* __restrict__ yout0, bf16* __restrict__ yout1, int ostride,
    const float* __restrict__ lng, const float* __restrict__ lnb,
    int steps, int Mtot, int rev0, int rev1)
{
  int dir = blockIdx.y;
  const bf16*  xw = dir ? xw1 : xw0;
  const bf16*  Wh = dir ? Wh1 : Wh0;
  const float* bh = dir ? bh1 : bh0;
  bf16* yout = dir ? yout1 : yout0;
  int rev = dir ? rev1 : rev0;

  __shared__ __align__(16) bf16 hbuf[16][264];          //  8448 B
  __shared__ __align__(16) bf16 xbuf[2][8][3][16][32];  // 49152 B
  __shared__ bf16 ldspad[12544];                        // 25088 B -> 82688 total

  int tid = threadIdx.x;
  int w = tid >> 6, lane = tid & 63, r16 = lane & 15, g4 = lane >> 4;
  int rowbase = (int)blockIdx.x * 16;
  int c0 = w * 32 + r16, c1 = c0 + 16;
  if (steps == 0) ldspad[tid] = (bf16)0.f;   // keep the pad alive (runtime cond)

  for (int i2 = tid; i2 < 528; i2 += 512) ((bf16x8*)hbuf)[i2] = (bf16x8){};

  // Wh -> registers, pinned (cannot be rematerialized from memory)
  f32x4 wr0[8], wz0[8], wn0[8], wr1[8], wz1[8], wn1[8];
  {
    const bf16* W0 = Wh + (size_t)c0 * 256;
    const bf16* W1 = Wh + (size_t)c1 * 256;
#pragma unroll
    for (int kk = 0; kk < 8; kk++) {
      int k0 = kk * 32 + g4 * 8;
      wr0[kk] = *(const f32x4*)(W0 + k0);          asm volatile("" : "+v"(wr0[kk]));
      wz0[kk] = *(const f32x4*)(W0 + 65536 + k0);  asm volatile("" : "+v"(wz0[kk]));
      wn0[kk] = *(const f32x4*)(W0 + 131072 + k0); asm volatile("" : "+v"(wn0[kk]));
      wr1[kk] = *(const f32x4*)(W1 + k0);          asm volatile("" : "+v"(wr1[kk]));
      wz1[kk] = *(const f32x4*)(W1 + 65536 + k0);  asm volatile("" : "+v"(wz1[kk]));
      wn1[kk] = *(const f32x4*)(W1 + 131072 + k0); asm volatile("" : "+v"(wn1[kk]));
    }
  }
  float bhn0 = bh[c0 + 512], bhn1 = bh[c1 + 512];

  // stage step st into xbuf[b]: wave w DMAs exactly its own gate-slice region
  auto stage = [&](int b, int st) {
    int row = rowbase + (lane >> 2);
    const bf16* s = xw + ((size_t)st * Mtot + row) * 768 + w * 32 + (lane & 3) * 8;
    gload16(s,       &xbuf[b][w][0][0][0]);
    gload16(s + 256, &xbuf[b][w][1][0][0]);
    gload16(s + 512, &xbuf[b][w][2][0][0]);
  };
  stage(0, rev ? steps - 1 : 0);
  wg_barrier();   // hbuf zero-init visible (xbuf readiness is via vmcnt)

  for (int i = 0; i < steps; i++) {
    int cur = i & 1;
    int st = rev ? steps - 1 - i : i;
    if (i + 1 < steps) {
      stage(cur ^ 1, rev ? steps - 2 - i : i + 1);
      asm volatile("s_waitcnt vmcnt(3)" ::: "memory");   // xbuf[cur] ready
    } else {
      asm volatile("s_waitcnt vmcnt(0)" ::: "memory");
    }
    __builtin_amdgcn_sched_barrier(0);

    float hn0[4], hn1[4];
    {
      f32x4 a0 = {0,0,0,0}, a1 = {0,0,0,0}, a2 = {0,0,0,0};
#pragma unroll
      for (int kk = 0; kk < 8; kk++) {
        bf16x8 a = *(const bf16x8*)&hbuf[r16][kk * 32 + g4 * 8];
        a0 = mfma16(a, asbf(wr0[kk]), a0);
        a1 = mfma16(a, asbf(wz0[kk]), a1);
        a2 = mfma16(a, asbf(wn0[kk]), a2);
      }
#pragma unroll
      for (int j = 0; j < 4; j++) {
        int m = g4 * 4 + j;
        float r = sigm((float)xbuf[cur][w][0][m][r16] + a0[j]);
        float z = sigm((float)xbuf[cur][w][1][m][r16] + a1[j]);
        float n = tanhf((float)xbuf[cur][w][2][m][r16] + r * (a2[j] + bhn0));
        hn0[j] = (1.f - z) * n + z * (float)hbuf[m][c0];
      }
    }
    {
      f32x4 a0 = {0,0,0,0}, a1 = {0,0,0,0}, a2 = {0,0,0,0};
#pragma unroll
      for (int kk = 0; kk < 8; kk++) {
        bf16x8 a = *(const bf16x8*)&hbuf[r16][kk * 32 + g4 * 8];
        a0 = mfma16(a, asbf(wr1[kk]), a0);
        a1 = mfma16(a, asbf(wz1[kk]), a1);
        a2 = mfma16(a, asbf(wn1[kk]), a2);
      }
#pragma unroll
      for (int j = 0; j < 4; j++) {
        int m = g4 * 4 + j;
        float r = sigm((float)xbuf[cur][w][0][m][r16 + 16] + a0[j]);
        float z = sigm((float)xbuf[cur][w][1][m][r16 + 16] + a1[j]);
        float n = tanhf((float)xbuf[cur][w][2][m][r16 + 16] + r * (a2[j] + bhn1));
        hn1[j] = (1.f - z) * n + z * (float)hbuf[m][c1];
      }
    }
    wg_barrier();                    // all hbuf / xbuf[cur] reads done WG-wide
#pragma unroll
    for (int j = 0; j < 4; j++) {
      int m = g4 * 4 + j;
      hbuf[m][c0] = (bf16)hn0[j];
      hbuf[m][c1] = (bf16)hn1[j];
    }
    if (!lng) {
#pragma unroll
      for (int j = 0; j < 4; j++) {
        size_t ro = ((size_t)st * Mtot + rowbase + g4 * 4 + j) * ostride;
        yout[ro + c0] = (bf16)hn0[j];
        yout[ro + c1] = (bf16)hn1[j];
      }
    }
    wg_barrier();                    // h_{i+1} visible
    if (lng) {
      // fused LN(256); recurrence keeps raw h. wave -> rows 2w, 2w+1
#pragma unroll
      for (int rr = 0; rr < 2; rr++) {
        int r = w * 2 + rr;
        bf16x4 v4 = *(const bf16x4*)&hbuf[r][lane * 4];
        float v[4]; float sm = 0.f, sq = 0.f;
#pragma unroll
        for (int j = 0; j < 4; j++) { v[j] = (float)v4[j]; sm += v[j]; sq += v[j] * v[j]; }
        for (int msk = 32; msk; msk >>= 1) { sm += __shfl_xor(sm, msk); sq += __shfl_xor(sq, msk); }
        float mu  = sm * (1.f / 256.f);
        float var = sq * (1.f / 256.f) - mu * mu;
        float inv = rsqrtf(fmaxf(var, 0.f) + 1e-5f);
        bf16x4 o;
#pragma unroll
        for (int j = 0; j < 4; j++)
          o[j] = (bf16)((v[j] - mu) * inv * lng[lane * 4 + j] + lnb[lane * 4 + j]);
        *(bf16x4*)&yout[((size_t)st * Mtot + rowbase + r) * ostride + lane * 4] = o;
      }
    }
  }
}

// ---------------------------------------------------------------------------
// Sentence tail, t-parallel: block (r-tile, tg) accumulates 4 t's of
// tanh(LN512(hf||hb) @ linW^T + b) into part[tg] (f32). grid (c/16, 8).
// ---------------------------------------------------------------------------
__global__ __launch_bounds__(256) void sent_tail_part(
    const bf16* __restrict__ hf, const bf16* __restrict__ hb,
    const float* __restrict__ gam, const float* __restrict__ bet,
    const bf16* __restrict__ W, const float* __restrict__ bias,
    float* __restrict__ part, int c)
{
  int wave = threadIdx.x >> 6;
  int lane = threadIdx.x & 63;
  int r16 = lane & 15, g4 = lane >> 4;
  int r0 = (int)blockIdx.x << 4;
  int tg = blockIdx.y;
  size_t rowoff = (size_t)(r0 + r16) * 256;

  f32x4 ms0 = {0,0,0,0}, ms1 = {0,0,0,0}, ms2 = {0,0,0,0}, ms3 = {0,0,0,0};

  for (int tt = 0; tt < 4; tt++) {
    int t = tg * 4 + tt;
    const bf16* pf = hf + (size_t)t * c * 256 + rowoff;
    const bf16* pb = hb + (size_t)t * c * 256 + rowoff;
    bf16x8 xv[16];
    float s = 0.f, sq = 0.f;
#pragma unroll
    for (int kk = 0; kk < 16; kk++) {
      int k0 = kk * 32 + g4 * 8;
      xv[kk] = (kk < 8) ? *(const bf16x8*)(pf + k0) : *(const bf16x8*)(pb + k0 - 256);
#pragma unroll
      for (int j = 0; j < 8; j++) { float f = (float)xv[kk][j]; s += f; sq += f * f; }
    }
    s  += __shfl_xor(s, 16);  s  += __shfl_xor(s, 32);
    sq += __shfl_xor(sq, 16); sq += __shfl_xor(sq, 32);
    float mu  = s * (1.f / 512.f);
    float var = sq * (1.f / 512.f) - mu * mu;
    float inv = rsqrtf(fmaxf(var, 0.f) + 1e-5f);
#pragma unroll
    for (int kk = 0; kk < 16; kk++) {
      int k0 = kk * 32 + g4 * 8;
      float ga[8], be[8];
      *(float4*)(ga)     = *(const float4*)(gam + k0);
      *(float4*)(ga + 4) = *(const float4*)(gam + k0 + 4);
      *(float4*)(be)     = *(const float4*)(bet + k0);
      *(float4*)(be + 4) = *(const float4*)(bet + k0 + 4);
#pragma unroll
      for (int j = 0; j < 8; j++)
        xv[kk][j] = (bf16)(((float)xv[kk][j] - mu) * inv * ga[j] + be[j]);
    }
#pragma unroll
    for (int tc = 0; tc < 4; tc++) {
      int cj = wave * 64 + tc * 16;
      const bf16* wp = W + (size_t)(cj + r16) * 512;
      f32x4 acc = {0,0,0,0};
#pragma unroll
      for (int kk = 0; kk < 16; kk++)
        acc = mfma16(xv[kk], *(const bf16x8*)(wp + kk * 32 + g4 * 8), acc);
      float bb = bias[cj + r16];
      f32x4* msp = (tc == 0) ? &ms0 : (tc == 1) ? &ms1 : (tc == 2) ? &ms2 : &ms3;
#pragma unroll
      for (int j = 0; j < 4; j++) (*msp)[j] += tanhf(acc[j] + bb);
    }
  }
#pragma unroll
  for (int tc = 0; tc < 4; tc++) {
    int cj = wave * 64 + tc * 16;
    f32x4 ms = (tc == 0) ? ms0 : (tc == 1) ? ms1 : (tc == 2) ? ms2 : ms3;
#pragma unroll
    for (int j = 0; j < 4; j++)
      part[((size_t)tg * c + r0 + g4 * 4 + j) * 256 + cj + r16] = ms[j];
  }
}

// sum 8 partials, scale 1/32, write bf16. grid = c blocks x 256 thr.
__global__ __launch_bounds__(256) void tail_reduce(
    const float* __restrict__ part, bf16* __restrict__ out, int c)
{
  int idx = blockIdx.x * 256 + threadIdx.x;
  float s = 0.f;
#pragma unroll
  for (int g = 0; g < 8; g++) s += part[(size_t)g * c * 256 + idx];
  out[idx] = (bf16)(s * 0.03125f);
}

// ---------------------------------------------------------------------------
// Fused LN(512) + sigmoid head: out(3072x2 f32). Wave per row.
// ---------------------------------------------------------------------------
__global__ __launch_bounds__(256) void ln_out_head(
    const bf16* __restrict__ X, const float* __restrict__ lng, const float* __restrict__ lnb,
    const float* __restrict__ W, const float* __restrict__ bias, float* __restrict__ out)
{
  int w = threadIdx.x >> 6, lane = threadIdx.x & 63;
  int row = (int)blockIdx.x * 4 + w;
  bf16x8 v8 = *(const bf16x8*)&X[(size_t)row * 512 + lane * 8];
  float v[8]; float sm = 0.f, sq = 0.f;
#pragma unroll
  for (int j = 0; j < 8; j++) { v[j] = (float)v8[j]; sm += v[j]; sq += v[j] * v[j]; }
  for (int msk = 32; msk; msk >>= 1) { sm += __shfl_xor(sm, msk); sq += __shfl_xor(sq, msk); }
  float mu  = sm * (1.f / 512.f);
  float var = sq * (1.f / 512.f) - mu * mu;
  float inv = rsqrtf(fmaxf(var, 0.f) + 1e-5f);
  float a0 = 0.f, a1 = 0.f;
  int base = lane * 8;
#pragma unroll
  for (int j = 0; j < 8; j++) {
    float y = (v[j] - mu) * inv * lng[base + j] + lnb[base + j];
    a0 += y * W[base + j];
    a1 += y * W[512 + base + j];
  }
  for (int msk = 32; msk; msk >>= 1) { a0 += __shfl_xor(a0, msk); a1 += __shfl_xor(a1, msk); }
  if (lane == 0) {
    out[(size_t)row * 2 + 0] = sigm(a0 + bias[0]);
    out[(size_t)row * 2 + 1] = sigm(a1 + bias[1]);
  }
}

// ---------------------------------------------------------------------------
extern "C" void kernel_launch(void* const* d_in, const int* in_sizes, int n_in,
                              void* d_out, int out_size, void* d_ws, size_t ws_size,
                              hipStream_t stream)
{
  (void)in_sizes; (void)n_in; (void)out_size;
  const int*   tokens = (const int*)d_in[0];
  const float* emb    = (const float*)d_in[1];
  auto fp = [&](int i) { return (const float*)d_in[i]; };
  const float *s_WiF = fp(2),  *s_WhF = fp(3),  *s_biF = fp(4),  *s_bhF = fp(5);
  const float *s_lnF_g = fp(6), *s_lnF_b = fp(7);
  const float *s_Wi_f = fp(8),  *s_Wh_f = fp(9),  *s_bi_f = fp(10), *s_bh_f = fp(11);
  const float *s_Wi_b = fp(12), *s_Wh_b = fp(13), *s_bi_b = fp(14), *s_bh_b = fp(15);
  const float *s_ln_g = fp(16), *s_ln_b = fp(17), *s_linW = fp(18), *s_linb = fp(19);
  const float *dWiF = fp(20), *dWhF = fp(21), *dbiF = fp(22), *dbhF = fp(23);
  const float *d_lnF_g = fp(24), *d_lnF_b = fp(25);
  const float *dWi_f = fp(26), *dWh_f = fp(27), *dbi_f = fp(28), *dbh_f = fp(29);
  const float *dWi_b = fp(30), *dWh_b = fp(31), *dbi_b = fp(32), *dbh_b = fp(33);
  const float *d_ln_g = fp(34), *d_ln_b = fp(35), *out_W = fp(36), *out_b = fp(37);

  const int T = 32, S = 96;
  const int GW = 196608;

  // ---- converted bf16 weights + emb + folded biases ----
  bf16* wc = (bf16*)d_ws;
  bf16 *c_sWiF = wc,         *c_sWhF = wc + GW;
  bf16 *c_sWif = wc + 2*GW,  *c_sWhf = wc + 3*GW;
  bf16 *c_sWib = wc + 4*GW,  *c_sWhb = wc + 5*GW;
  bf16 *c_dWiF = wc + 6*GW,  *c_dWhF = wc + 7*GW;
  bf16 *c_dWif = wc + 8*GW,  *c_dWhf = wc + 9*GW;
  bf16 *c_dWib = wc + 10*GW, *c_dWhb = wc + 11*GW;
  bf16 *c_linW = wc + 12*GW;
  const size_t WB = (size_t)(12 * GW + 131072) * 2;       // 4,980,736
  bf16* embb = (bf16*)((char*)d_ws + WB);                 // 32000x256 bf16
  const size_t EB = (size_t)32000 * 256 * 2;              // 16,384,000
  float* bmod = (float*)((char*)d_ws + WB + EB);          // 6 x 768 f32
  const size_t BMB = 6 * 768 * 4;                         // 18,432

  conv13<<<dim3(192, 13), 256, 0, stream>>>(
      s_WiF, s_WhF, s_Wi_f, s_Wh_f, s_Wi_b, s_Wh_b,
      dWiF, dWhF, dWi_f, dWh_f, dWi_b, dWh_b, s_linW, wc);
  cvt_bf16<<<8000, 256, 0, stream>>>(emb, embb, 2048000);
  prep_bias<<<dim3(3, 6), 256, 0, stream>>>(
      s_biF, s_bhF, s_bi_f, s_bh_f, s_bi_b, s_bh_b,
      dbiF, dbhF, dbi_f, dbh_f, dbi_b, dbh_b, bmod);
  const float *bm_sF = bmod, *bm_sf = bmod + 768, *bm_sb = bmod + 1536;
  const float *bm_dF = bmod + 2304, *bm_df = bmod + 3072, *bm_db = bmod + 3840;

  // ---- fixed doc-side buffers ----
  char* ws = (char*)d_ws + WB + EB + BMB;
  bf16* store = (bf16*)ws;                           // (3072, 256)
  bf16* yd1ln = store + (size_t)3072 * 256;          // (3072, 256)
  bf16* ybid  = yd1ln + (size_t)3072 * 256;          // (3072, 512)
  bf16* xw_u  = ybid  + (size_t)3072 * 512;          // (3072, 768)
  bf16* xwdf  = xw_u  + (size_t)3072 * 768;
  bf16* xwdb  = xwdf  + (size_t)3072 * 768;
  const size_t fixedB = WB + EB + BMB
      + ((size_t)3072 * 256 * 2 + (size_t)3072 * 512 + (size_t)3 * 3072 * 768) * 2;

  // ---- sentence chunk size (rows; multiple of 64) ----
  // per-row: xw 49152 + y1ln 16384 + hf 16384 + hb 16384 = 98304 B
  int c = 3072;
  while (c > 192 && fixedB + (size_t)98304 * c > ws_size) c >>= 1;
  char* cb = (char*)d_ws + fixedB;
  bf16*  xw   = (bf16*)cb;                           // (T*c, 768), reused 3x
  bf16*  y1ln = (bf16*)(cb + (size_t)49152 * c);     // (T*c, 256)
  bf16*  hf   = (bf16*)(cb + (size_t)65536 * c);     // (T*c, 256)
  bf16*  hb   = (bf16*)(cb + (size_t)81920 * c);     // (T*c, 256)
  float* part = (float*)cb;                          // (8, c, 256) f32, alias xw

  // ---- sentence encoder, chunked ----
  for (int base = 0; base < 3072; base += c) {
    const int* tkb = tokens + (size_t)base * 32;
    xw_gather_gemm<<<dim3((c / 64) * 12, T), 256, 0, stream>>>(
        tkb, embb, c_sWiF, bm_sF, xw, c);
    pgru<<<dim3(c / 16, 1), 512, 0, stream>>>(
        xw, c_sWhF, s_bhF, nullptr, nullptr, nullptr,
        y1ln, nullptr, 256, s_lnF_g, s_lnF_b, T, c, 0, 0);
    xw_gemm<<<dim3((T * c / 64) * 12, 1), 256, 0, stream>>>(
        y1ln, c_sWif, bm_sf, xw, nullptr, nullptr, nullptr);
    pgru<<<dim3(c / 16, 1), 512, 0, stream>>>(
        xw, c_sWhf, s_bh_f, nullptr, nullptr, nullptr,
        hf, nullptr, 256, nullptr, nullptr, T, c, 0, 0);
    xw_gemm<<<dim3((T * c / 64) * 12, 1), 256, 0, stream>>>(
        y1ln, c_sWib, bm_sb, xw, nullptr, nullptr, nullptr);
    pgru<<<dim3(c / 16, 1), 512, 0, stream>>>(
        xw, c_sWhb, s_bh_b, nullptr, nullptr, nullptr,
        hb, nullptr, 256, nullptr, nullptr, T, c, 1, 0);
    sent_tail_part<<<dim3(c / 16, 8), 256, 0, stream>>>(
        hf, hb, s_ln_g, s_ln_b, c_linW, s_linb, part, c);
    tail_reduce<<<c, 256, 0, stream>>>(part, store + (size_t)base * 256, c);
  }

  // ---- document encoder ----
  xw_gemm<<<dim3((3072 / 64) * 12, 1), 256, 0, stream>>>(
      store, c_dWiF, bm_dF, xw_u, nullptr, nullptr, nullptr);
  pgru<<<dim3(2, 1), 512, 0, stream>>>(
      xw_u, c_dWhF, dbhF, nullptr, nullptr, nullptr,
      yd1ln, nullptr, 256, d_lnF_g, d_lnF_b, S, 32, 0, 0);
  xw_gemm<<<dim3((3072 / 64) * 12, 2), 256, 0, stream>>>(
      yd1ln, c_dWif, bm_df, xwdf, c_dWib, bm_db, xwdb);
  pgru<<<dim3(2, 2), 512, 0, stream>>>(
      xwdf, c_dWhf, dbh_f, xwdb, c_dWhb, dbh_b,
      ybid, ybid + 256, 512, nullptr, nullptr, S, 32, 0, 1);
  ln_out_head<<<768, 256, 0, stream>>>(ybid, d_ln_g, d_ln_b, out_W, out_b,
                                       (float*)d_out);
}

// Round 10
// 3632.314 us; speedup vs baseline: 1.0654x; 1.0008x over previous
//
#include <hip/hip_runtime.h>

// ---------------------------------------------------------------------------
// SequenceTaggle: hierarchical GRU (sentence enc -> doc enc) on MI355X.
// V=32000 E=256 H=256 O=2 S=96 T=32 B=32, N = S*B = 3072.
// DEVICE DTYPES: float tensors f32; tokens int32; output f32.
// Internal: bf16 MFMA, f32 accumulation.
// pgru v6: 1024 thr = 16 waves; wave owns 16 cols -> Wh slice = 96 VGPR,
// fits the mandatory 128-VGPR budget (4 waves/SIMD) -> NO spill. h in LDS.
// xw staged via global_load_lds into per-wave self-regions, counted vmcnt.
// bh_r/bh_z folded into the xw GEMM bias (prep_bias); only bhn in pgru.
// ---------------------------------------------------------------------------

typedef __bf16 bf16;
typedef __bf16 bf16x8 __attribute__((ext_vector_type(8)));
typedef __bf16 bf16x4 __attribute__((ext_vector_type(4)));
typedef float  f32x4  __attribute__((ext_vector_type(4)));

static __device__ __forceinline__ f32x4 mfma16(bf16x8 a, bf16x8 b, f32x4 c) {
  // A: lane row = lane&15, k = (lane>>4)*8 + j ; B: lane col = lane&15, same k
  // D: col = lane&15, row = (lane>>4)*4 + reg
  return __builtin_amdgcn_mfma_f32_16x16x32_bf16(a, b, c, 0, 0, 0);
}
static __device__ __forceinline__ float sigm(float x) { return 1.f / (1.f + __expf(-x)); }
static __device__ __forceinline__ bf16x8 asbf(f32x4 v) {
  union { f32x4 f; bf16x8 b; } u; u.f = v; return u.b;
}
// Raw barrier: LDS-visibility only; global loads/stores stay in flight.
static __device__ __forceinline__ void wg_barrier() {
  asm volatile("s_waitcnt lgkmcnt(0)" ::: "memory");
  __builtin_amdgcn_s_barrier();
  __builtin_amdgcn_sched_barrier(0);
}
// 16B global -> LDS DMA (LDS dest wave-uniform base + lane*16)
static __device__ __forceinline__ void gload16(const bf16* g, bf16* l) {
  __builtin_amdgcn_global_load_lds(
      (const __attribute__((address_space(1))) void*)g,
      (__attribute__((address_space(3))) void*)l, 16, 0, 0);
}

// ---- generic f32 -> bf16 (n4 float4 groups) ----
__global__ __launch_bounds__(256) void cvt_bf16(
    const float* __restrict__ s, bf16* __restrict__ d, int n4)
{
  int i = blockIdx.x * 256 + threadIdx.x;
  if (i < n4) {
    float4 v = ((const float4*)s)[i];
    bf16x4 o;
    o[0] = (bf16)v.x; o[1] = (bf16)v.y; o[2] = (bf16)v.z; o[3] = (bf16)v.w;
    ((bf16x4*)d)[i] = o;
  }
}

// ---- one-shot weight conversion: 12 GRU mats (196608 ea) + linW (131072) ----
__global__ __launch_bounds__(256) void conv13(
    const float* s0, const float* s1, const float* s2, const float* s3,
    const float* s4, const float* s5, const float* s6, const float* s7,
    const float* s8, const float* s9, const float* s10, const float* s11,
    const float* s12, bf16* __restrict__ dst)
{
  const float* srcs[13] = {s0,s1,s2,s3,s4,s5,s6,s7,s8,s9,s10,s11,s12};
  int m = blockIdx.y;
  int n4 = (m == 12) ? 32768 : 49152;
  int i = blockIdx.x * 256 + threadIdx.x;
  if (i >= n4) return;
  float4 v = ((const float4*)srcs[m])[i];
  bf16x4 o;
  o[0] = (bf16)v.x; o[1] = (bf16)v.y; o[2] = (bf16)v.z; o[3] = (bf16)v.w;
  ((bf16x4*)(dst + (size_t)m * 196608))[i] = o;
}

// ---- bmod[g][i] = bi[i] + (i<512 ? bh[i] : 0)  for 6 GRUs. grid (3,6). ----
__global__ __launch_bounds__(256) void prep_bias(
    const float* b0i, const float* b0h, const float* b1i, const float* b1h,
    const float* b2i, const float* b2h, const float* b3i, const float* b3h,
    const float* b4i, const float* b4h, const float* b5i, const float* b5h,
    float* __restrict__ out)
{
  const float* bis[6] = {b0i,b1i,b2i,b3i,b4i,b5i};
  const float* bhs[6] = {b0h,b1h,b2h,b3h,b4h,b5h};
  int g = blockIdx.y;
  int i = blockIdx.x * 256 + threadIdx.x;
  if (i < 768)
    out[g * 768 + i] = bis[g][i] + (i < 512 ? bhs[g][i] : 0.f);
}

// ---------------------------------------------------------------------------
// xw = X(M x 256) @ W(768 x 256)^T + bias -> (M x 768) bf16.
// Wave handles 64 rows x 16 cols (weight frags reused 4x). grid.x=(M/64)*12.
// ---------------------------------------------------------------------------
__global__ __launch_bounds__(256) void xw_gemm(
    const bf16* __restrict__ X,
    const bf16* __restrict__ W0, const float* __restrict__ b0, bf16* __restrict__ o0,
    const bf16* __restrict__ W1, const float* __restrict__ b1, bf16* __restrict__ o1)
{
  const bf16* W = blockIdx.y ? W1 : W0;
  const float* bias = blockIdx.y ? b1 : b0;
  bf16* out = blockIdx.y ? o1 : o0;
  int wave = (int)blockIdx.x * 4 + (threadIdx.x >> 6);
  int g64 = wave / 48, ct = wave - g64 * 48;
  int lane = threadIdx.x & 63;
  int r16 = lane & 15, g4 = lane >> 4;
  const bf16* wp = W + (size_t)(ct * 16 + r16) * 256;
  const bf16* xb = X + ((size_t)g64 * 64 + r16) * 256;
  f32x4 a0 = {0,0,0,0}, a1 = {0,0,0,0}, a2 = {0,0,0,0}, a3 = {0,0,0,0};
#pragma unroll
  for (int kk = 0; kk < 8; kk++) {
    int k0 = kk * 32 + g4 * 8;
    bf16x8 wf = *(const bf16x8*)(wp + k0);
    a0 = mfma16(*(const bf16x8*)(xb + k0), wf, a0);
    a1 = mfma16(*(const bf16x8*)(xb + 4096 + k0), wf, a1);
    a2 = mfma16(*(const bf16x8*)(xb + 8192 + k0), wf, a2);
    a3 = mfma16(*(const bf16x8*)(xb + 12288 + k0), wf, a3);
  }
  float bv = bias[ct * 16 + r16];
#pragma unroll
  for (int rt = 0; rt < 4; rt++) {
    f32x4 ac = rt == 0 ? a0 : rt == 1 ? a1 : rt == 2 ? a2 : a3;
#pragma unroll
    for (int j = 0; j < 4; j++)
      out[(size_t)(g64 * 64 + rt * 16 + g4 * 4 + j) * 768 + ct * 16 + r16] = (bf16)(ac[j] + bv);
  }
}

// ---------------------------------------------------------------------------
// xw1 = emb[tok] @ W^T + bias (gather fused). blockIdx.y = t.
// ---------------------------------------------------------------------------
__global__ __launch_bounds__(256) void xw_gather_gemm(
    const int* __restrict__ tok, const bf16* __restrict__ embb,
    const bf16* __restrict__ W, const float* __restrict__ bias,
    bf16* __restrict__ out, int c)
{
  int t = blockIdx.y;
  int wave = (int)blockIdx.x * 4 + (threadIdx.x >> 6);
  int g64 = wave / 48, ct = wave - g64 * 48;
  int lane = threadIdx.x & 63;
  int r16 = lane & 15, g4 = lane >> 4;
  const bf16* wp = W + (size_t)(ct * 16 + r16) * 256;
  const bf16* ap[4];
#pragma unroll
  for (int rt = 0; rt < 4; rt++) {
    int n = g64 * 64 + rt * 16 + r16;
    int tk = tok[((n >> 5) << 10) + (t << 5) + (n & 31)];
    ap[rt] = embb + (size_t)tk * 256;
  }
  f32x4 a0 = {0,0,0,0}, a1 = {0,0,0,0}, a2 = {0,0,0,0}, a3 = {0,0,0,0};
#pragma unroll
  for (int kk = 0; kk < 8; kk++) {
    int k0 = kk * 32 + g4 * 8;
    bf16x8 wf = *(const bf16x8*)(wp + k0);
    a0 = mfma16(*(const bf16x8*)(ap[0] + k0), wf, a0);
    a1 = mfma16(*(const bf16x8*)(ap[1] + k0), wf, a1);
    a2 = mfma16(*(const bf16x8*)(ap[2] + k0), wf, a2);
    a3 = mfma16(*(const bf16x8*)(ap[3] + k0), wf, a3);
  }
  float bv = bias[ct * 16 + r16];
#pragma unroll
  for (int rt = 0; rt < 4; rt++) {
    f32x4 ac = rt == 0 ? a0 : rt == 1 ? a1 : rt == 2 ? a2 : a3;
#pragma unroll
    for (int j = 0; j < 4; j++)
      out[((size_t)t * c + g64 * 64 + rt * 16 + g4 * 4 + j) * 768 + ct * 16 + r16] = (bf16)(ac[j] + bv);
  }
}

// ---------------------------------------------------------------------------
// Persistent GRU v6. 1024 thr = 16 waves; wave w owns 16 cols. Wh slice in
// VGPRs: 24 bf16x8 = 96 VGPR -> fits the 128 budget (4 waves/SIMD mandatory
// at 1024 thr) -> no spill. 16 batch rows per WG in LDS. xw staged via
// global_load_lds into per-wave self-regions xbuf[b][w][3][16][16] (two 16B
// DMAs; gate-1 double-written with identical bytes); counted vmcnt(2).
// ---------------------------------------------------------------------------
__global__ __launch_bounds__(1024)
__attribute__((amdgpu_waves_per_eu(4, 4)))
void pgru(
    const bf16* __restrict__ xw0, const bf16* __restrict__ Wh0, const float* __restrict__ bh0,
    const bf16* __restrict__ xw1, const bf16* __restrict__ Wh1, const float* __restrict__ bh1,
    bf16* __restrict__ yout0, bf16* __restrict__ yout1, int ostride,
    const float* __restrict__ lng, const float* __restrict__ lnb,
    int steps, int Mtot, int rev0, int rev1)
{
  int dir = blockIdx.y;
  const bf16*  xw = dir ? xw1 : xw0;
  const bf16*  Wh = dir ? Wh1 : Wh0;
  const float* bh = dir ? bh1 : bh0;
  bf16* yout = dir ? yout1 : yout0;
  int rev = dir ? rev1 : rev0;

  __shared__ __align__(16) bf16 hbuf[16][264];          //  8448 B
  __shared__ __align__(16) bf16 xbuf[2][16][3][16][16]; // 49152 B

  int tid = threadIdx.x;
  int w = tid >> 6, lane = tid & 63, r16 = lane & 15, g4 = lane >> 4;
  int rowbase = (int)blockIdx.x * 16;
  int c0 = w * 16 + r16;

  for (int i2 = tid; i2 < 528; i2 += 1024) ((bf16x8*)hbuf)[i2] = (bf16x8){};

  // Wh slice -> registers (96 VGPR), pinned
  f32x4 wr[8], wz[8], wn[8];
  {
    const bf16* W0 = Wh + (size_t)c0 * 256;
#pragma unroll
    for (int kk = 0; kk < 8; kk++) {
      int k0 = kk * 32 + g4 * 8;
      wr[kk] = *(const f32x4*)(W0 + k0);          asm volatile("" : "+v"(wr[kk]));
      wz[kk] = *(const f32x4*)(W0 + 65536 + k0);  asm volatile("" : "+v"(wz[kk]));
      wn[kk] = *(const f32x4*)(W0 + 131072 + k0); asm volatile("" : "+v"(wn[kk]));
    }
  }
  float bhn0 = bh[c0 + 512];

  // stage step st into xbuf[b][w]: region [3][16][16]; DMA1 covers gates 0-1,
  // DMA2 covers gates 1-2 (gate 1 double-written, identical bytes).
  int m_ = (lane & 31) >> 1;
  int k_ = (lane & 1) * 8;
  int gsel = (lane >> 5) * 256;
  auto stage = [&](int b, int st) {
    const bf16* s1 = xw + ((size_t)st * Mtot + rowbase + m_) * 768 + gsel + w * 16 + k_;
    gload16(s1,       &xbuf[b][w][0][0][0]);
    gload16(s1 + 256, &xbuf[b][w][1][0][0]);
  };
  stage(0, rev ? steps - 1 : 0);

  for (int i = 0; i < steps; i++) {
    int cur = i & 1;
    int st = rev ? steps - 1 - i : i;
    if (i + 1 < steps) {
      stage(cur ^ 1, rev ? steps - 2 - i : i + 1);
      asm volatile("s_waitcnt vmcnt(2)" ::: "memory");   // xbuf[cur] (mine) ready
    } else {
      asm volatile("s_waitcnt vmcnt(0)" ::: "memory");
    }
    __builtin_amdgcn_sched_barrier(0);
    wg_barrier();                    // (A) h_i commits visible WG-wide

    f32x4 a0 = {0,0,0,0}, a1 = {0,0,0,0}, a2 = {0,0,0,0};
#pragma unroll
    for (int kk = 0; kk < 8; kk++) {
      bf16x8 a = *(const bf16x8*)&hbuf[r16][kk * 32 + g4 * 8];
      a0 = mfma16(a, asbf(wr[kk]), a0);
      a1 = mfma16(a, asbf(wz[kk]), a1);
      a2 = mfma16(a, asbf(wn[kk]), a2);
    }
    float hn[4];
#pragma unroll
    for (int j = 0; j < 4; j++) {
      int m = g4 * 4 + j;
      float r = sigm((float)xbuf[cur][w][0][m][r16] + a0[j]);
      float z = sigm((float)xbuf[cur][w][1][m][r16] + a1[j]);
      float n = tanhf((float)xbuf[cur][w][2][m][r16] + r * (a2[j] + bhn0));
      hn[j] = (1.f - z) * n + z * (float)hbuf[m][c0];
    }
    wg_barrier();                    // (B) all hbuf reads done WG-wide
#pragma unroll
    for (int j = 0; j < 4; j++)
      hbuf[g4 * 4 + j][c0] = (bf16)hn[j];
    if (!lng) {
#pragma unroll
      for (int j = 0; j < 4; j++) {
        size_t ro = ((size_t)st * Mtot + rowbase + g4 * 4 + j) * ostride;
        yout[ro + c0] = (bf16)hn[j];
      }
    } else {
      wg_barrier();                  // (C) h_{i+1} visible; LN reads full rows
      // fused LN(256); recurrence keeps raw h. wave w -> row w.
      bf16x4 v4 = *(const bf16x4*)&hbuf[w][lane * 4];
      float v[4]; float sm = 0.f, sq = 0.f;
#pragma unroll
      for (int j = 0; j < 4; j++) { v[j] = (float)v4[j]; sm += v[j]; sq += v[j] * v[j]; }
      for (int msk = 32; msk; msk >>= 1) { sm += __shfl_xor(sm, msk); sq += __shfl_xor(sq, msk); }
      float mu  = sm * (1.f / 256.f);
      float var = sq * (1.f / 256.f) - mu * mu;
      float inv = rsqrtf(fmaxf(var, 0.f) + 1e-5f);
      bf16x4 o;
#pragma unroll
      for (int j = 0; j < 4; j++)
        o[j] = (bf16)((v[j] - mu) * inv * lng[lane * 4 + j] + lnb[lane * 4 + j]);
      *(bf16x4*)&yout[((size_t)st * Mtot + rowbase + w) * ostride + lane * 4] = o;
    }
  }
}

// ---------------------------------------------------------------------------
// Sentence tail, t-parallel: block (r-tile, tg) accumulates 4 t's of
// tanh(LN512(hf||hb) @ linW^T + b) into part[tg] (f32). grid (c/16, 8).
// ---------------------------------------------------------------------------
__global__ __launch_bounds__(256) void sent_tail_part(
    const bf16* __restrict__ hf, const bf16* __restrict__ hb,
    const float* __restrict__ gam, const float* __restrict__ bet,
    const bf16* __restrict__ W, const float* __restrict__ bias,
    float* __restrict__ part, int c)
{
  int wave = threadIdx.x >> 6;
  int lane = threadIdx.x & 63;
  int r16 = lane & 15, g4 = lane >> 4;
  int r0 = (int)blockIdx.x << 4;
  int tg = blockIdx.y;
  size_t rowoff = (size_t)(r0 + r16) * 256;

  f32x4 ms0 = {0,0,0,0}, ms1 = {0,0,0,0}, ms2 = {0,0,0,0}, ms3 = {0,0,0,0};

  for (int tt = 0; tt < 4; tt++) {
    int t = tg * 4 + tt;
    const bf16* pf = hf + (size_t)t * c * 256 + rowoff;
    const bf16* pb = hb + (size_t)t * c * 256 + rowoff;
    bf16x8 xv[16];
    float s = 0.f, sq = 0.f;
#pragma unroll
    for (int kk = 0; kk < 16; kk++) {
      int k0 = kk * 32 + g4 * 8;
      xv[kk] = (kk < 8) ? *(const bf16x8*)(pf + k0) : *(const bf16x8*)(pb + k0 - 256);
#pragma unroll
      for (int j = 0; j < 8; j++) { float f = (float)xv[kk][j]; s += f; sq += f * f; }
    }
    s  += __shfl_xor(s, 16);  s  += __shfl_xor(s, 32);
    sq += __shfl_xor(sq, 16); sq += __shfl_xor(sq, 32);
    float mu  = s * (1.f / 512.f);
    float var = sq * (1.f / 512.f) - mu * mu;
    float inv = rsqrtf(fmaxf(var, 0.f) + 1e-5f);
#pragma unroll
    for (int kk = 0; kk < 16; kk++) {
      int k0 = kk * 32 + g4 * 8;
      float ga[8], be[8];
      *(float4*)(ga)     = *(const float4*)(gam + k0);
      *(float4*)(ga + 4) = *(const float4*)(gam + k0 + 4);
      *(float4*)(be)     = *(const float4*)(bet + k0);
      *(float4*)(be + 4) = *(const float4*)(bet + k0 + 4);
#pragma unroll
      for (int j = 0; j < 8; j++)
        xv[kk][j] = (bf16)(((float)xv[kk][j] - mu) * inv * ga[j] + be[j]);
    }
#pragma unroll
    for (int tc = 0; tc < 4; tc++) {
      int cj = wave * 64 + tc * 16;
      const bf16* wp = W + (size_t)(cj + r16) * 512;
      f32x4 acc = {0,0,0,0};
#pragma unroll
      for (int kk = 0; kk < 16; kk++)
        acc = mfma16(xv[kk], *(const bf16x8*)(wp + kk * 32 + g4 * 8), acc);
      float bb = bias[cj + r16];
      f32x4* msp = (tc == 0) ? &ms0 : (tc == 1) ? &ms1 : (tc == 2) ? &ms2 : &ms3;
#pragma unroll
      for (int j = 0; j < 4; j++) (*msp)[j] += tanhf(acc[j] + bb);
    }
  }
#pragma unroll
  for (int tc = 0; tc < 4; tc++) {
    int cj = wave * 64 + tc * 16;
    f32x4 ms = (tc == 0) ? ms0 : (tc == 1) ? ms1 : (tc == 2) ? ms2 : ms3;
#pragma unroll
    for (int j = 0; j < 4; j++)
      part[((size_t)tg * c + r0 + g4 * 4 + j) * 256 + cj + r16] = ms[j];
  }
}

// sum 8 partials, scale 1/32, write bf16. grid = c blocks x 256 thr.
__global__ __launch_bounds__(256) void tail_reduce(
    const float* __restrict__ part, bf16* __restrict__ out, int c)
{
  int idx = blockIdx.x * 256 + threadIdx.x;
  float s = 0.f;
#pragma unroll
  for (int g = 0; g < 8; g++) s += part[(size_t)g * c * 256 + idx];
  out[idx] = (bf16)(s * 0.03125f);
}

// ---------------------------------------------------------------------------
// Fused LN(512) + sigmoid head: out(3072x2 f32). Wave per row.
// ---------------------------------------------------------------------------
__global__ __launch_bounds__(256) void ln_out_head(
    const bf16* __restrict__ X, const float* __restrict__ lng, const float* __restrict__ lnb,
    const float* __restrict__ W, const float* __restrict__ bias, float* __restrict__ out)
{
  int w = threadIdx.x >> 6, lane = threadIdx.x & 63;
  int row = (int)blockIdx.x * 4 + w;
  bf16x8 v8 = *(const bf16x8*)&X[(size_t)row * 512 + lane * 8];
  float v[8]; float sm = 0.f, sq = 0.f;
#pragma unroll
  for (int j = 0; j < 8; j++) { v[j] = (float)v8[j]; sm += v[j]; sq += v[j] * v[j]; }
  for (int msk = 32; msk; msk >>= 1) { sm += __shfl_xor(sm, msk); sq += __shfl_xor(sq, msk); }
  float mu  = sm * (1.f / 512.f);
  float var = sq * (1.f / 512.f) - mu * mu;
  float inv = rsqrtf(fmaxf(var, 0.f) + 1e-5f);
  float a0 = 0.f, a1 = 0.f;
  int base = lane * 8;
#pragma unroll
  for (int j = 0; j < 8; j++) {
    float y = (v[j] - mu) * inv * lng[base + j] + lnb[base + j];
    a0 += y * W[base + j];
    a1 += y * W[512 + base + j];
  }
  for (int msk = 32; msk; msk >>= 1) { a0 += __shfl_xor(a0, msk); a1 += __shfl_xor(a1, msk); }
  if (lane == 0) {
    out[(size_t)row * 2 + 0] = sigm(a0 + bias[0]);
    out[(size_t)row * 2 + 1] = sigm(a1 + bias[1]);
  }
}

// ---------------------------------------------------------------------------
extern "C" void kernel_launch(void* const* d_in, const int* in_sizes, int n_in,
                              void* d_out, int out_size, void* d_ws, size_t ws_size,
                              hipStream_t stream)
{
  (void)in_sizes; (void)n_in; (void)out_size;
  const int*   tokens = (const int*)d_in[0];
  const float* emb    = (const float*)d_in[1];
  auto fp = [&](int i) { return (const float*)d_in[i]; };
  const float *s_WiF = fp(2),  *s_WhF = fp(3),  *s_biF = fp(4),  *s_bhF = fp(5);
  const float *s_lnF_g = fp(6), *s_lnF_b = fp(7);
  const float *s_Wi_f = fp(8),  *s_Wh_f = fp(9),  *s_bi_f = fp(10), *s_bh_f = fp(11);
  const float *s_Wi_b = fp(12), *s_Wh_b = fp(13), *s_bi_b = fp(14), *s_bh_b = fp(15);
  const float *s_ln_g = fp(16), *s_ln_b = fp(17), *s_linW = fp(18), *s_linb = fp(19);
  const float *dWiF = fp(20), *dWhF = fp(21), *dbiF = fp(22), *dbhF = fp(23);
  const float *d_lnF_g = fp(24), *d_lnF_b = fp(25);
  const float *dWi_f = fp(26), *dWh_f = fp(27), *dbi_f = fp(28), *dbh_f = fp(29);
  const float *dWi_b = fp(30), *dWh_b = fp(31), *dbi_b = fp(32), *dbh_b = fp(33);
  const float *d_ln_g = fp(34), *d_ln_b = fp(35), *out_W = fp(36), *out_b = fp(37);

  const int T = 32, S = 96;
  const int GW = 196608;

  // ---- converted bf16 weights + emb + folded biases ----
  bf16* wc = (bf16*)d_ws;
  bf16 *c_sWiF = wc,         *c_sWhF = wc + GW;
  bf16 *c_sWif = wc + 2*GW,  *c_sWhf = wc + 3*GW;
  bf16 *c_sWib = wc + 4*GW,  *c_sWhb = wc + 5*GW;
  bf16 *c_dWiF = wc + 6*GW,  *c_dWhF = wc + 7*GW;
  bf16 *c_dWif = wc + 8*GW,  *c_dWhf = wc + 9*GW;
  bf16 *c_dWib = wc + 10*GW, *c_dWhb = wc + 11*GW;
  bf16 *c_linW = wc + 12*GW;
  const size_t WB = (size_t)(12 * GW + 131072) * 2;       // 4,980,736
  bf16* embb = (bf16*)((char*)d_ws + WB);                 // 32000x256 bf16
  const size_t EB = (size_t)32000 * 256 * 2;              // 16,384,000
  float* bmod = (float*)((char*)d_ws + WB + EB);          // 6 x 768 f32
  const size_t BMB = 6 * 768 * 4;                         // 18,432

  conv13<<<dim3(192, 13), 256, 0, stream>>>(
      s_WiF, s_WhF, s_Wi_f, s_Wh_f, s_Wi_b, s_Wh_b,
      dWiF, dWhF, dWi_f, dWh_f, dWi_b, dWh_b, s_linW, wc);
  cvt_bf16<<<8000, 256, 0, stream>>>(emb, embb, 2048000);
  prep_bias<<<dim3(3, 6), 256, 0, stream>>>(
      s_biF, s_bhF, s_bi_f, s_bh_f, s_bi_b, s_bh_b,
      dbiF, dbhF, dbi_f, dbh_f, dbi_b, dbh_b, bmod);
  const float *bm_sF = bmod, *bm_sf = bmod + 768, *bm_sb = bmod + 1536;
  const float *bm_dF = bmod + 2304, *bm_df = bmod + 3072, *bm_db = bmod + 3840;

  // ---- fixed doc-side buffers ----
  char* ws = (char*)d_ws + WB + EB + BMB;
  bf16* store = (bf16*)ws;                           // (3072, 256)
  bf16* yd1ln = store + (size_t)3072 * 256;          // (3072, 256)
  bf16* ybid  = yd1ln + (size_t)3072 * 256;          // (3072, 512)
  bf16* xw_u  = ybid  + (size_t)3072 * 512;          // (3072, 768)
  bf16* xwdf  = xw_u  + (size_t)3072 * 768;
  bf16* xwdb  = xwdf  + (size_t)3072 * 768;
  const size_t fixedB = WB + EB + BMB
      + ((size_t)3072 * 256 * 2 + (size_t)3072 * 512 + (size_t)3 * 3072 * 768) * 2;

  // ---- sentence chunk size (rows; multiple of 64) ----
  // per-row: xw 49152 + y1ln 16384 + hf 16384 + hb 16384 = 98304 B
  int c = 3072;
  while (c > 192 && fixedB + (size_t)98304 * c > ws_size) c >>= 1;
  char* cb = (char*)d_ws + fixedB;
  bf16*  xw   = (bf16*)cb;                           // (T*c, 768), reused 3x
  bf16*  y1ln = (bf16*)(cb + (size_t)49152 * c);     // (T*c, 256)
  bf16*  hf   = (bf16*)(cb + (size_t)65536 * c);     // (T*c, 256)
  bf16*  hb   = (bf16*)(cb + (size_t)81920 * c);     // (T*c, 256)
  float* part = (float*)cb;                          // (8, c, 256) f32, alias xw

  // ---- sentence encoder, chunked ----
  for (int base = 0; base < 3072; base += c) {
    const int* tkb = tokens + (size_t)base * 32;
    xw_gather_gemm<<<dim3((c / 64) * 12, T), 256, 0, stream>>>(
        tkb, embb, c_sWiF, bm_sF, xw, c);
    pgru<<<dim3(c / 16, 1), 1024, 0, stream>>>(
        xw, c_sWhF, s_bhF, nullptr, nullptr, nullptr,
        y1ln, nullptr, 256, s_lnF_g, s_lnF_b, T, c, 0, 0);
    xw_gemm<<<dim3((T * c / 64) * 12, 1), 256, 0, stream>>>(
        y1ln, c_sWif, bm_sf, xw, nullptr, nullptr, nullptr);
    pgru<<<dim3(c / 16, 1), 1024, 0, stream>>>(
        xw, c_sWhf, s_bh_f, nullptr, nullptr, nullptr,
        hf, nullptr, 256, nullptr, nullptr, T, c, 0, 0);
    xw_gemm<<<dim3((T * c / 64) * 12, 1), 256, 0, stream>>>(
        y1ln, c_sWib, bm_sb, xw, nullptr, nullptr, nullptr);
    pgru<<<dim3(c / 16, 1), 1024, 0, stream>>>(
        xw, c_sWhb, s_bh_b, nullptr, nullptr, nullptr,
        hb, nullptr, 256, nullptr, nullptr, T, c, 1, 0);
    sent_tail_part<<<dim3(c / 16, 8), 256, 0, stream>>>(
        hf, hb, s_ln_g, s_ln_b, c_linW, s_linb, part, c);
    tail_reduce<<<c, 256, 0, stream>>>(part, store + (size_t)base * 256, c);
  }

  // ---- document encoder ----
  xw_gemm<<<dim3((3072 / 64) * 12, 1), 256, 0, stream>>>(
      store, c_dWiF, bm_dF, xw_u, nullptr, nullptr, nullptr);
  pgru<<<dim3(2, 1), 1024, 0, stream>>>(
      xw_u, c_dWhF, dbhF, nullptr, nullptr, nullptr,
      yd1ln, nullptr, 256, d_lnF_g, d_lnF_b, S, 32, 0, 0);
  xw_gemm<<<dim3((3072 / 64) * 12, 2), 256, 0, stream>>>(
      yd1ln, c_dWif, bm_df, xwdf, c_dWib, bm_db, xwdb);
  pgru<<<dim3(2, 2), 1024, 0, stream>>>(
      xwdf, c_dWhf, dbh_f, xwdb, c_dWhb, dbh_b,
      ybid, ybid + 256, 512, nullptr, nullptr, S, 32, 0, 1);
  ln_out_head<<<768, 256, 0, stream>>>(ybid, d_ln_g, d_ln_b, out_W, out_b,
                                       (float*)d_out);
}

// Round 11
// 3587.338 us; speedup vs baseline: 1.0788x; 1.0125x over previous
//
#include <hip/hip_runtime.h>

// ---------------------------------------------------------------------------
// SequenceTaggle: hierarchical GRU (sentence enc -> doc enc) on MI355X.
// V=32000 E=256 H=256 O=2 S=96 T=32 B=32, N = S*B = 3072.
// DEVICE DTYPES: float tensors f32; tokens int32; output f32.
// Internal: bf16 MFMA, f32 accumulation.
// pgru v7: 512 thr = 8 waves; wave owns 32 cols -> Wh slice = 192 VGPR.
// Static LDS 82.7 KB (triple-buffered xbuf, really used) -> only 1 WG/CU
// fits -> 2 waves/SIMD -> allocator VGPR budget 256 -> weights do NOT spill.
// xw staged via global_load_lds into per-wave self-regions, counted vmcnt.
// bh_r/bh_z folded into the xw GEMM bias (prep_bias); only bhn in pgru.
// ---------------------------------------------------------------------------

typedef __bf16 bf16;
typedef __bf16 bf16x8 __attribute__((ext_vector_type(8)));
typedef __bf16 bf16x4 __attribute__((ext_vector_type(4)));
typedef float  f32x4  __attribute__((ext_vector_type(4)));

static __device__ __forceinline__ f32x4 mfma16(bf16x8 a, bf16x8 b, f32x4 c) {
  // A: lane row = lane&15, k = (lane>>4)*8 + j ; B: lane col = lane&15, same k
  // D: col = lane&15, row = (lane>>4)*4 + reg
  return __builtin_amdgcn_mfma_f32_16x16x32_bf16(a, b, c, 0, 0, 0);
}
static __device__ __forceinline__ float sigm(float x) { return 1.f / (1.f + __expf(-x)); }
static __device__ __forceinline__ bf16x8 asbf(f32x4 v) {
  union { f32x4 f; bf16x8 b; } u; u.f = v; return u.b;
}
// Raw barrier: LDS-visibility only; global loads/stores stay in flight.
static __device__ __forceinline__ void wg_barrier() {
  asm volatile("s_waitcnt lgkmcnt(0)" ::: "memory");
  __builtin_amdgcn_s_barrier();
  __builtin_amdgcn_sched_barrier(0);
}
// 16B global -> LDS DMA (LDS dest wave-uniform base + lane*16)
static __device__ __forceinline__ void gload16(const bf16* g, bf16* l) {
  __builtin_amdgcn_global_load_lds(
      (const __attribute__((address_space(1))) void*)g,
      (__attribute__((address_space(3))) void*)l, 16, 0, 0);
}

// ---- generic f32 -> bf16 (n4 float4 groups) ----
__global__ __launch_bounds__(256) void cvt_bf16(
    const float* __restrict__ s, bf16* __restrict__ d, int n4)
{
  int i = blockIdx.x * 256 + threadIdx.x;
  if (i < n4) {
    float4 v = ((const float4*)s)[i];
    bf16x4 o;
    o[0] = (bf16)v.x; o[1] = (bf16)v.y; o[2] = (bf16)v.z; o[3] = (bf16)v.w;
    ((bf16x4*)d)[i] = o;
  }
}

// ---- one-shot weight conversion: 12 GRU mats (196608 ea) + linW (131072) ----
__global__ __launch_bounds__(256) void conv13(
    const float* s0, const float* s1, const float* s2, const float* s3,
    const float* s4, const float* s5, const float* s6, const float* s7,
    const float* s8, const float* s9, const float* s10, const float* s11,
    const float* s12, bf16* __restrict__ dst)
{
  const float* srcs[13] = {s0,s1,s2,s3,s4,s5,s6,s7,s8,s9,s10,s11,s12};
  int m = blockIdx.y;
  int n4 = (m == 12) ? 32768 : 49152;
  int i = blockIdx.x * 256 + threadIdx.x;
  if (i >= n4) return;
  float4 v = ((const float4*)srcs[m])[i];
  bf16x4 o;
  o[0] = (bf16)v.x; o[1] = (bf16)v.y; o[2] = (bf16)v.z; o[3] = (bf16)v.w;
  ((bf16x4*)(dst + (size_t)m * 196608))[i] = o;
}

// ---- bmod[g][i] = bi[i] + (i<512 ? bh[i] : 0)  for 6 GRUs. grid (3,6). ----
__global__ __launch_bounds__(256) void prep_bias(
    const float* b0i, const float* b0h, const float* b1i, const float* b1h,
    const float* b2i, const float* b2h, const float* b3i, const float* b3h,
    const float* b4i, const float* b4h, const float* b5i, const float* b5h,
    float* __restrict__ out)
{
  const float* bis[6] = {b0i,b1i,b2i,b3i,b4i,b5i};
  const float* bhs[6] = {b0h,b1h,b2h,b3h,b4h,b5h};
  int g = blockIdx.y;
  int i = blockIdx.x * 256 + threadIdx.x;
  if (i < 768)
    out[g * 768 + i] = bis[g][i] + (i < 512 ? bhs[g][i] : 0.f);
}

// ---------------------------------------------------------------------------
// xw = X(M x 256) @ W(768 x 256)^T + bias -> (M x 768) bf16.
// Wave handles 64 rows x 16 cols (weight frags reused 4x). grid.x=(M/64)*12.
// ---------------------------------------------------------------------------
__global__ __launch_bounds__(256) void xw_gemm(
    const bf16* __restrict__ X,
    const bf16* __restrict__ W0, const float* __restrict__ b0, bf16* __restrict__ o0,
    const bf16* __restrict__ W1, const float* __restrict__ b1, bf16* __restrict__ o1)
{
  const bf16* W = blockIdx.y ? W1 : W0;
  const float* bias = blockIdx.y ? b1 : b0;
  bf16* out = blockIdx.y ? o1 : o0;
  int wave = (int)blockIdx.x * 4 + (threadIdx.x >> 6);
  int g64 = wave / 48, ct = wave - g64 * 48;
  int lane = threadIdx.x & 63;
  int r16 = lane & 15, g4 = lane >> 4;
  const bf16* wp = W + (size_t)(ct * 16 + r16) * 256;
  const bf16* xb = X + ((size_t)g64 * 64 + r16) * 256;
  f32x4 a0 = {0,0,0,0}, a1 = {0,0,0,0}, a2 = {0,0,0,0}, a3 = {0,0,0,0};
#pragma unroll
  for (int kk = 0; kk < 8; kk++) {
    int k0 = kk * 32 + g4 * 8;
    bf16x8 wf = *(const bf16x8*)(wp + k0);
    a0 = mfma16(*(const bf16x8*)(xb + k0), wf, a0);
    a1 = mfma16(*(const bf16x8*)(xb + 4096 + k0), wf, a1);
    a2 = mfma16(*(const bf16x8*)(xb + 8192 + k0), wf, a2);
    a3 = mfma16(*(const bf16x8*)(xb + 12288 + k0), wf, a3);
  }
  float bv = bias[ct * 16 + r16];
#pragma unroll
  for (int rt = 0; rt < 4; rt++) {
    f32x4 ac = rt == 0 ? a0 : rt == 1 ? a1 : rt == 2 ? a2 : a3;
#pragma unroll
    for (int j = 0; j < 4; j++)
      out[(size_t)(g64 * 64 + rt * 16 + g4 * 4 + j) * 768 + ct * 16 + r16] = (bf16)(ac[j] + bv);
  }
}

// ---------------------------------------------------------------------------
// xw1 = emb[tok] @ W^T + bias (gather fused). blockIdx.y = t.
// ---------------------------------------------------------------------------
__global__ __launch_bounds__(256) void xw_gather_gemm(
    const int* __restrict__ tok, const bf16* __restrict__ embb,
    const bf16* __restrict__ W, const float* __restrict__ bias,
    bf16* __restrict__ out, int c)
{
  int t = blockIdx.y;
  int wave = (int)blockIdx.x * 4 + (threadIdx.x >> 6);
  int g64 = wave / 48, ct = wave - g64 * 48;
  int lane = threadIdx.x & 63;
  int r16 = lane & 15, g4 = lane >> 4;
  const bf16* wp = W + (size_t)(ct * 16 + r16) * 256;
  const bf16* ap[4];
#pragma unroll
  for (int rt = 0; rt < 4; rt++) {
    int n = g64 * 64 + rt * 16 + r16;
    int tk = tok[((n >> 5) << 10) + (t << 5) + (n & 31)];
    ap[rt] = embb + (size_t)tk * 256;
  }
  f32x4 a0 = {0,0,0,0}, a1 = {0,0,0,0}, a2 = {0,0,0,0}, a3 = {0,0,0,0};
#pragma unroll
  for (int kk = 0; kk < 8; kk++) {
    int k0 = kk * 32 + g4 * 8;
    bf16x8 wf = *(const bf16x8*)(wp + k0);
    a0 = mfma16(*(const bf16x8*)(ap[0] + k0), wf, a0);
    a1 = mfma16(*(const bf16x8*)(ap[1] + k0), wf, a1);
    a2 = mfma16(*(const bf16x8*)(ap[2] + k0), wf, a2);
    a3 = mfma16(*(const bf16x8*)(ap[3] + k0), wf, a3);
  }
  float bv = bias[ct * 16 + r16];
#pragma unroll
  for (int rt = 0; rt < 4; rt++) {
    f32x4 ac = rt == 0 ? a0 : rt == 1 ? a1 : rt == 2 ? a2 : a3;
#pragma unroll
    for (int j = 0; j < 4; j++)
      out[((size_t)t * c + g64 * 64 + rt * 16 + g4 * 4 + j) * 768 + ct * 16 + r16] = (bf16)(ac[j] + bv);
  }
}

// ---------------------------------------------------------------------------
// Persistent GRU v7. 512 thr = 8 waves; wave w owns 32 cols (2 tiles).
// Wh slice pinned in VGPRs (48 f32x4 = 192). Static LDS 82.7 KB (hbuf +
// TRIPLE-buffered xbuf, all genuinely used) -> 1 WG/CU -> 2 waves/SIMD ->
// VGPR budget 256 -> no spill. xw staged via global_load_lds into per-wave
// self-regions xbuf[i%3][w][3][16][32]; counted vmcnt(3), never 0 mid-loop.
// ---------------------------------------------------------------------------
__global__ __launch_bounds__(512)
void pgru(
    const bf16* __restrict__ xw0, const bf16* __restrict__ Wh0, const float* __restrict__ bh0,
    const bf16* __restrict__ xw1, const bf16* __restrict__ Wh1, const float* __restrict__ bh1,
    bf16* __restrict__ yout0, bf16* __restrict__ yout1, int ostride,
    const float* __restrict__ lng, const float* __restrict__ lnb,
    int steps, int Mtot, int rev0, int rev1)
{
  int dir = blockIdx.y;
  const bf16*  xw = dir ? xw1 : xw0;
  const bf16*  Wh = dir ? Wh1 : Wh0;
  const float* bh = dir ? bh1 : bh0;
  bf16* yout = dir ? yout1 : yout0;
  int rev = dir ? rev1 : rev0;

  __shared__ __align__(16) bf16 hbuf[16][280];          //  8960 B
  __shared__ __align__(16) bf16 xbuf[3][8][3][16][32];  // 73728 B -> 82688 B total

  int tid = threadIdx.x;
  int w = tid >> 6, lane = tid & 63, r16 = lane & 15, g4 = lane >> 4;
  int rowbase = (int)blockIdx.x * 16;
  int c0 = w * 32 + r16, c1 = c0 + 16;

  for (int i2 = tid; i2 < 560; i2 += 512) ((bf16x8*)hbuf)[i2] = (bf16x8){};

  // Wh slices -> registers, pinned (192 VGPR)
  f32x4 wr0[8], wz0[8], wn0[8], wr1[8], wz1[8], wn1[8];
  {
    const bf16* W0 = Wh + (size_t)c0 * 256;
    const bf16* W1 = Wh + (size_t)c1 * 256;
#pragma unroll
    for (int kk = 0; kk < 8; kk++) {
      int k0 = kk * 32 + g4 * 8;
      wr0[kk] = *(const f32x4*)(W0 + k0);          asm volatile("" : "+v"(wr0[kk]));
      wz0[kk] = *(const f32x4*)(W0 + 65536 + k0);  asm volatile("" : "+v"(wz0[kk]));
      wn0[kk] = *(const f32x4*)(W0 + 131072 + k0); asm volatile("" : "+v"(wn0[kk]));
      wr1[kk] = *(const f32x4*)(W1 + k0);          asm volatile("" : "+v"(wr1[kk]));
      wz1[kk] = *(const f32x4*)(W1 + 65536 + k0);  asm volatile("" : "+v"(wz1[kk]));
      wn1[kk] = *(const f32x4*)(W1 + 131072 + k0); asm volatile("" : "+v"(wn1[kk]));
    }
  }
  float bhn0 = bh[c0 + 512], bhn1 = bh[c1 + 512];

  // stage step st into xbuf[b][w]: 3 DMAs (one per gate region [16][32]).
  int m_ = lane >> 2;
  int k_ = (lane & 3) * 8;
  auto stage = [&](int b, int st) {
    const bf16* s = xw + ((size_t)st * Mtot + rowbase + m_) * 768 + w * 32 + k_;
    gload16(s,       &xbuf[b][w][0][0][0]);
    gload16(s + 256, &xbuf[b][w][1][0][0]);
    gload16(s + 512, &xbuf[b][w][2][0][0]);
  };
  stage(0, rev ? steps - 1 : 0);
  wg_barrier();   // hbuf zero-init visible (xbuf readiness via vmcnt)

  for (int i = 0; i < steps; i++) {
    int cur = i % 3;
    int st = rev ? steps - 1 - i : i;
    if (i + 1 < steps) {
      stage((i + 1) % 3, rev ? steps - 2 - i : i + 1);
      asm volatile("s_waitcnt vmcnt(3)" ::: "memory");   // my xbuf[cur] ready
    } else {
      asm volatile("s_waitcnt vmcnt(0)" ::: "memory");
    }
    __builtin_amdgcn_sched_barrier(0);

    float hn0[4], hn1[4];
    {
      f32x4 a0 = {0,0,0,0}, a1 = {0,0,0,0}, a2 = {0,0,0,0};
#pragma unroll
      for (int kk = 0; kk < 8; kk++) {
        bf16x8 a = *(const bf16x8*)&hbuf[r16][kk * 32 + g4 * 8];
        a0 = mfma16(a, asbf(wr0[kk]), a0);
        a1 = mfma16(a, asbf(wz0[kk]), a1);
        a2 = mfma16(a, asbf(wn0[kk]), a2);
      }
#pragma unroll
      for (int j = 0; j < 4; j++) {
        int m = g4 * 4 + j;
        float r = sigm((float)xbuf[cur][w][0][m][r16] + a0[j]);
        float z = sigm((float)xbuf[cur][w][1][m][r16] + a1[j]);
        float n = tanhf((float)xbuf[cur][w][2][m][r16] + r * (a2[j] + bhn0));
        hn0[j] = (1.f - z) * n + z * (float)hbuf[m][c0];
      }
    }
    {
      f32x4 a0 = {0,0,0,0}, a1 = {0,0,0,0}, a2 = {0,0,0,0};
#pragma unroll
      for (int kk = 0; kk < 8; kk++) {
        bf16x8 a = *(const bf16x8*)&hbuf[r16][kk * 32 + g4 * 8];
        a0 = mfma16(a, asbf(wr1[kk]), a0);
        a1 = mfma16(a, asbf(wz1[kk]), a1);
        a2 = mfma16(a, asbf(wn1[kk]), a2);
      }
#pragma unroll
      for (int j = 0; j < 4; j++) {
        int m = g4 * 4 + j;
        float r = sigm((float)xbuf[cur][w][0][m][r16 + 16] + a0[j]);
        float z = sigm((float)xbuf[cur][w][1][m][r16 + 16] + a1[j]);
        float n = tanhf((float)xbuf[cur][w][2][m][r16 + 16] + r * (a2[j] + bhn1));
        hn1[j] = (1.f - z) * n + z * (float)hbuf[m][c1];
      }
    }
    wg_barrier();                    // all hbuf / xbuf[cur] reads done WG-wide
#pragma unroll
    for (int j = 0; j < 4; j++) {
      int m = g4 * 4 + j;
      hbuf[m][c0] = (bf16)hn0[j];
      hbuf[m][c1] = (bf16)hn1[j];
    }
    if (!lng) {
#pragma unroll
      for (int j = 0; j < 4; j++) {
        size_t ro = ((size_t)st * Mtot + rowbase + g4 * 4 + j) * ostride;
        yout[ro + c0] = (bf16)hn0[j];
        yout[ro + c1] = (bf16)hn1[j];
      }
    }
    wg_barrier();                    // h_{i+1} visible
    if (lng) {
      // fused LN(256); recurrence keeps raw h. wave -> rows 2w, 2w+1
#pragma unroll
      for (int rr = 0; rr < 2; rr++) {
        int r = w * 2 + rr;
        bf16x4 v4 = *(const bf16x4*)&hbuf[r][lane * 4];
        float v[4]; float sm = 0.f, sq = 0.f;
#pragma unroll
        for (int j = 0; j < 4; j++) { v[j] = (float)v4[j]; sm += v[j]; sq += v[j] * v[j]; }
        for (int msk = 32; msk; msk >>= 1) { sm += __shfl_xor(sm, msk); sq += __shfl_xor(sq, msk); }
        float mu  = sm * (1.f / 256.f);
        float var = sq * (1.f / 256.f) - mu * mu;
        float inv = rsqrtf(fmaxf(var, 0.f) + 1e-5f);
        bf16x4 o;
#pragma unroll
        for (int j = 0; j < 4; j++)
          o[j] = (bf16)((v[j] - mu) * inv * lng[lane * 4 + j] + lnb[lane * 4 + j]);
        *(bf16x4*)&yout[((size_t)st * Mtot + rowbase + r) * ostride + lane * 4] = o;
      }
    }
  }
}

// ---------------------------------------------------------------------------
// Sentence tail, t-parallel: block (r-tile, tg) accumulates 4 t's of
// tanh(LN512(hf||hb) @ linW^T + b) into part[tg] (f32). grid (c/16, 8).
// ---------------------------------------------------------------------------
__global__ __launch_bounds__(256) void sent_tail_part(
    const bf16* __restrict__ hf, const bf16* __restrict__ hb,
    const float* __restrict__ gam, const float* __restrict__ bet,
    const bf16* __restrict__ W, const float* __restrict__ bias,
    float* __restrict__ part, int c)
{
  int wave = threadIdx.x >> 6;
  int lane = threadIdx.x & 63;
  int r16 = lane & 15, g4 = lane >> 4;
  int r0 = (int)blockIdx.x << 4;
  int tg = blockIdx.y;
  size_t rowoff = (size_t)(r0 + r16) * 256;

  f32x4 ms0 = {0,0,0,0}, ms1 = {0,0,0,0}, ms2 = {0,0,0,0}, ms3 = {0,0,0,0};

  for (int tt = 0; tt < 4; tt++) {
    int t = tg * 4 + tt;
    const bf16* pf = hf + (size_t)t * c * 256 + rowoff;
    const bf16* pb = hb + (size_t)t * c * 256 + rowoff;
    bf16x8 xv[16];
    float s = 0.f, sq = 0.f;
#pragma unroll
    for (int kk = 0; kk < 16; kk++) {
      int k0 = kk * 32 + g4 * 8;
      xv[kk] = (kk < 8) ? *(const bf16x8*)(pf + k0) : *(const bf16x8*)(pb + k0 - 256);
#pragma unroll
      for (int j = 0; j < 8; j++) { float f = (float)xv[kk][j]; s += f; sq += f * f; }
    }
    s  += __shfl_xor(s, 16);  s  += __shfl_xor(s, 32);
    sq += __shfl_xor(sq, 16); sq += __shfl_xor(sq, 32);
    float mu  = s * (1.f / 512.f);
    float var = sq * (1.f / 512.f) - mu * mu;
    float inv = rsqrtf(fmaxf(var, 0.f) + 1e-5f);
#pragma unroll
    for (int kk = 0; kk < 16; kk++) {
      int k0 = kk * 32 + g4 * 8;
      float ga[8], be[8];
      *(float4*)(ga)     = *(const float4*)(gam + k0);
      *(float4*)(ga + 4) = *(const float4*)(gam + k0 + 4);
      *(float4*)(be)     = *(const float4*)(bet + k0);
      *(float4*)(be + 4) = *(const float4*)(bet + k0 + 4);
#pragma unroll
      for (int j = 0; j < 8; j++)
        xv[kk][j] = (bf16)(((float)xv[kk][j] - mu) * inv * ga[j] + be[j]);
    }
#pragma unroll
    for (int tc = 0; tc < 4; tc++) {
      int cj = wave * 64 + tc * 16;
      const bf16* wp = W + (size_t)(cj + r16) * 512;
      f32x4 acc = {0,0,0,0};
#pragma unroll
      for (int kk = 0; kk < 16; kk++)
        acc = mfma16(xv[kk], *(const bf16x8*)(wp + kk * 32 + g4 * 8), acc);
      float bb = bias[cj + r16];
      f32x4* msp = (tc == 0) ? &ms0 : (tc == 1) ? &ms1 : (tc == 2) ? &ms2 : &ms3;
#pragma unroll
      for (int j = 0; j < 4; j++) (*msp)[j] += tanhf(acc[j] + bb);
    }
  }
#pragma unroll
  for (int tc = 0; tc < 4; tc++) {
    int cj = wave * 64 + tc * 16;
    f32x4 ms = (tc == 0) ? ms0 : (tc == 1) ? ms1 : (tc == 2) ? ms2 : ms3;
#pragma unroll
    for (int j = 0; j < 4; j++)
      part[((size_t)tg * c + r0 + g4 * 4 + j) * 256 + cj + r16] = ms[j];
  }
}

// sum 8 partials, scale 1/32, write bf16. grid = c blocks x 256 thr.
__global__ __launch_bounds__(256) void tail_reduce(
    const float* __restrict__ part, bf16* __restrict__ out, int c)
{
  int idx = blockIdx.x * 256 + threadIdx.x;
  float s = 0.f;
#pragma unroll
  for (int g = 0; g < 8; g++) s += part[(size_t)g * c * 256 + idx];
  out[idx] = (bf16)(s * 0.03125f);
}

// ---------------------------------------------------------------------------
// Fused LN(512) + sigmoid head: out(3072x2 f32). Wave per row.
// ---------------------------------------------------------------------------
__global__ __launch_bounds__(256) void ln_out_head(
    const bf16* __restrict__ X, const float* __restrict__ lng, const float* __restrict__ lnb,
    const float* __restrict__ W, const float* __restrict__ bias, float* __restrict__ out)
{
  int w = threadIdx.x >> 6, lane = threadIdx.x & 63;
  int row = (int)blockIdx.x * 4 + w;
  bf16x8 v8 = *(const bf16x8*)&X[(size_t)row * 512 + lane * 8];
  float v[8]; float sm = 0.f, sq = 0.f;
#pragma unroll
  for (int j = 0; j < 8; j++) { v[j] = (float)v8[j]; sm += v[j]; sq += v[j] * v[j]; }
  for (int msk = 32; msk; msk >>= 1) { sm += __shfl_xor(sm, msk); sq += __shfl_xor(sq, msk); }
  float mu  = sm * (1.f / 512.f);
  float var = sq * (1.f / 512.f) - mu * mu;
  float inv = rsqrtf(fmaxf(var, 0.f) + 1e-5f);
  float a0 = 0.f, a1 = 0.f;
  int base = lane * 8;
#pragma unroll
  for (int j = 0; j < 8; j++) {
    float y = (v[j] - mu) * inv * lng[base + j] + lnb[base + j];
    a0 += y * W[base + j];
    a1 += y * W[512 + base + j];
  }
  for (int msk = 32; msk; msk >>= 1) { a0 += __shfl_xor(a0, msk); a1 += __shfl_xor(a1, msk); }
  if (lane == 0) {
    out[(size_t)row * 2 + 0] = sigm(a0 + bias[0]);
    out[(size_t)row * 2 + 1] = sigm(a1 + bias[1]);
  }
}

// ---------------------------------------------------------------------------
extern "C" void kernel_launch(void* const* d_in, const int* in_sizes, int n_in,
                              void* d_out, int out_size, void* d_ws, size_t ws_size,
                              hipStream_t stream)
{
  (void)in_sizes; (void)n_in; (void)out_size;
  const int*   tokens = (const int*)d_in[0];
  const float* emb    = (const float*)d_in[1];
  auto fp = [&](int i) { return (const float*)d_in[i]; };
  const float *s_WiF = fp(2),  *s_WhF = fp(3),  *s_biF = fp(4),  *s_bhF = fp(5);
  const float *s_lnF_g = fp(6), *s_lnF_b = fp(7);
  const float *s_Wi_f = fp(8),  *s_Wh_f = fp(9),  *s_bi_f = fp(10), *s_bh_f = fp(11);
  const float *s_Wi_b = fp(12), *s_Wh_b = fp(13), *s_bi_b = fp(14), *s_bh_b = fp(15);
  const float *s_ln_g = fp(16), *s_ln_b = fp(17), *s_linW = fp(18), *s_linb = fp(19);
  const float *dWiF = fp(20), *dWhF = fp(21), *dbiF = fp(22), *dbhF = fp(23);
  const float *d_lnF_g = fp(24), *d_lnF_b = fp(25);
  const float *dWi_f = fp(26), *dWh_f = fp(27), *dbi_f = fp(28), *dbh_f = fp(29);
  const float *dWi_b = fp(30), *dWh_b = fp(31), *dbi_b = fp(32), *dbh_b = fp(33);
  const float *d_ln_g = fp(34), *d_ln_b = fp(35), *out_W = fp(36), *out_b = fp(37);

  const int T = 32, S = 96;
  const int GW = 196608;

  // ---- converted bf16 weights + emb + folded biases ----
  bf16* wc = (bf16*)d_ws;
  bf16 *c_sWiF = wc,         *c_sWhF = wc + GW;
  bf16 *c_sWif = wc + 2*GW,  *c_sWhf = wc + 3*GW;
  bf16 *c_sWib = wc + 4*GW,  *c_sWhb = wc + 5*GW;
  bf16 *c_dWiF = wc + 6*GW,  *c_dWhF = wc + 7*GW;
  bf16 *c_dWif = wc + 8*GW,  *c_dWhf = wc + 9*GW;
  bf16 *c_dWib = wc + 10*GW, *c_dWhb = wc + 11*GW;
  bf16 *c_linW = wc + 12*GW;
  const size_t WB = (size_t)(12 * GW + 131072) * 2;       // 4,980,736
  bf16* embb = (bf16*)((char*)d_ws + WB);                 // 32000x256 bf16
  const size_t EB = (size_t)32000 * 256 * 2;              // 16,384,000
  float* bmod = (float*)((char*)d_ws + WB + EB);          // 6 x 768 f32
  const size_t BMB = 6 * 768 * 4;                         // 18,432

  conv13<<<dim3(192, 13), 256, 0, stream>>>(
      s_WiF, s_WhF, s_Wi_f, s_Wh_f, s_Wi_b, s_Wh_b,
      dWiF, dWhF, dWi_f, dWh_f, dWi_b, dWh_b, s_linW, wc);
  cvt_bf16<<<8000, 256, 0, stream>>>(emb, embb, 2048000);
  prep_bias<<<dim3(3, 6), 256, 0, stream>>>(
      s_biF, s_bhF, s_bi_f, s_bh_f, s_bi_b, s_bh_b,
      dbiF, dbhF, dbi_f, dbh_f, dbi_b, dbh_b, bmod);
  const float *bm_sF = bmod, *bm_sf = bmod + 768, *bm_sb = bmod + 1536;
  const float *bm_dF = bmod + 2304, *bm_df = bmod + 3072, *bm_db = bmod + 3840;

  // ---- fixed doc-side buffers ----
  char* ws = (char*)d_ws + WB + EB + BMB;
  bf16* store = (bf16*)ws;                           // (3072, 256)
  bf16* yd1ln = store + (size_t)3072 * 256;          // (3072, 256)
  bf16* ybid  = yd1ln + (size_t)3072 * 256;          // (3072, 512)
  bf16* xw_u  = ybid  + (size_t)3072 * 512;          // (3072, 768)
  bf16* xwdf  = xw_u  + (size_t)3072 * 768;
  bf16* xwdb  = xwdf  + (size_t)3072 * 768;
  const size_t fixedB = WB + EB + BMB
      + ((size_t)3072 * 256 * 2 + (size_t)3072 * 512 + (size_t)3 * 3072 * 768) * 2;

  // ---- sentence chunk size (rows; multiple of 64) ----
  // per-row: xw 49152 + y1ln 16384 + hf 16384 + hb 16384 = 98304 B
  int c = 3072;
  while (c > 192 && fixedB + (size_t)98304 * c > ws_size) c >>= 1;
  char* cb = (char*)d_ws + fixedB;
  bf16*  xw   = (bf16*)cb;                           // (T*c, 768), reused 3x
  bf16*  y1ln = (bf16*)(cb + (size_t)49152 * c);     // (T*c, 256)
  bf16*  hf   = (bf16*)(cb + (size_t)65536 * c);     // (T*c, 256)
  bf16*  hb   = (bf16*)(cb + (size_t)81920 * c);     // (T*c, 256)
  float* part = (float*)cb;                          // (8, c, 256) f32, alias xw

  // ---- sentence encoder, chunked ----
  for (int base = 0; base < 3072; base += c) {
    const int* tkb = tokens + (size_t)base * 32;
    xw_gather_gemm<<<dim3((c / 64) * 12, T), 256, 0, stream>>>(
        tkb, embb, c_sWiF, bm_sF, xw, c);
    pgru<<<dim3(c / 16, 1), 512, 0, stream>>>(
        xw, c_sWhF, s_bhF, nullptr, nullptr, nullptr,
        y1ln, nullptr, 256, s_lnF_g, s_lnF_b, T, c, 0, 0);
    xw_gemm<<<dim3((T * c / 64) * 12, 1), 256, 0, stream>>>(
        y1ln, c_sWif, bm_sf, xw, nullptr, nullptr, nullptr);
    pgru<<<dim3(c / 16, 1), 512, 0, stream>>>(
        xw, c_sWhf, s_bh_f, nullptr, nullptr, nullptr,
        hf, nullptr, 256, nullptr, nullptr, T, c, 0, 0);
    xw_gemm<<<dim3((T * c / 64) * 12, 1), 256, 0, stream>>>(
        y1ln, c_sWib, bm_sb, xw, nullptr, nullptr, nullptr);
    pgru<<<dim3(c / 16, 1), 512, 0, stream>>>(
        xw, c_sWhb, s_bh_b, nullptr, nullptr, nullptr,
        hb, nullptr, 256, nullptr, nullptr, T, c, 1, 0);
    sent_tail_part<<<dim3(c / 16, 8), 256, 0, stream>>>(
        hf, hb, s_ln_g, s_ln_b, c_linW, s_linb, part, c);
    tail_reduce<<<c, 256, 0, stream>>>(part, store + (size_t)base * 256, c);
  }

  // ---- document encoder ----
  xw_gemm<<<dim3((3072 / 64) * 12, 1), 256, 0, stream>>>(
      store, c_dWiF, bm_dF, xw_u, nullptr, nullptr, nullptr);
  pgru<<<dim3(2, 1), 512, 0, stream>>>(
      xw_u, c_dWhF, dbhF, nullptr, nullptr, nullptr,
      yd1ln, nullptr, 256, d_lnF_g, d_lnF_b, S, 32, 0, 0);
  xw_gemm<<<dim3((3072 / 64) * 12, 2), 256, 0, stream>>>(
      yd1ln, c_dWif, bm_df, xwdf, c_dWib, bm_db, xwdb);
  pgru<<<dim3(2, 2), 512, 0, stream>>>(
      xwdf, c_dWhf, dbh_f, xwdb, c_dWhb, dbh_b,
      ybid, ybid + 256, 512, nullptr, nullptr, S, 32, 0, 1);
  ln_out_head<<<768, 256, 0, stream>>>(ybid, d_ln_g, d_ln_b, out_W, out_b,
                                       (float*)d_out);
}

// Round 12
// 3583.817 us; speedup vs baseline: 1.0798x; 1.0010x over previous
//
#include <hip/hip_runtime.h>

// ---------------------------------------------------------------------------
// SequenceTaggle: hierarchical GRU (sentence enc -> doc enc) on MI355X.
// V=32000 E=256 H=256 O=2 S=96 T=32 B=32, N = S*B = 3072.
// DEVICE DTYPES: float tensors f32; tokens int32; output f32.
// Internal: bf16 MFMA, f32 accumulation.
// pgru v8: 512 thr = 8 waves; wave owns 32 cols -> Wh slice = 192 VGPR.
// Static LDS 82.7 KB (triple-buffered xbuf, really used) -> 1 WG/CU (2
// waves/SIMD); amdgpu_waves_per_eu(1,2) lowers the allocator's default
// 4-waves/EU floor -> VGPR budget 256 -> pinned weights must not spill.
// xw staged via global_load_lds into per-wave self-regions, counted vmcnt.
// bh_r/bh_z folded into the xw GEMM bias (prep_bias); only bhn in pgru.
// ---------------------------------------------------------------------------

typedef __bf16 bf16;
typedef __bf16 bf16x8 __attribute__((ext_vector_type(8)));
typedef __bf16 bf16x4 __attribute__((ext_vector_type(4)));
typedef float  f32x4  __attribute__((ext_vector_type(4)));

static __device__ __forceinline__ f32x4 mfma16(bf16x8 a, bf16x8 b, f32x4 c) {
  // A: lane row = lane&15, k = (lane>>4)*8 + j ; B: lane col = lane&15, same k
  // D: col = lane&15, row = (lane>>4)*4 + reg
  return __builtin_amdgcn_mfma_f32_16x16x32_bf16(a, b, c, 0, 0, 0);
}
static __device__ __forceinline__ float sigm(float x) { return 1.f / (1.f + __expf(-x)); }
static __device__ __forceinline__ bf16x8 asbf(f32x4 v) {
  union { f32x4 f; bf16x8 b; } u; u.f = v; return u.b;
}
// Raw barrier: LDS-visibility only; global loads/stores stay in flight.
static __device__ __forceinline__ void wg_barrier() {
  asm volatile("s_waitcnt lgkmcnt(0)" ::: "memory");
  __builtin_amdgcn_s_barrier();
  __builtin_amdgcn_sched_barrier(0);
}
// 16B global -> LDS DMA (LDS dest wave-uniform base + lane*16)
static __device__ __forceinline__ void gload16(const bf16* g, bf16* l) {
  __builtin_amdgcn_global_load_lds(
      (const __attribute__((address_space(1))) void*)g,
      (__attribute__((address_space(3))) void*)l, 16, 0, 0);
}

// ---- generic f32 -> bf16 (n4 float4 groups) ----
__global__ __launch_bounds__(256) void cvt_bf16(
    const float* __restrict__ s, bf16* __restrict__ d, int n4)
{
  int i = blockIdx.x * 256 + threadIdx.x;
  if (i < n4) {
    float4 v = ((const float4*)s)[i];
    bf16x4 o;
    o[0] = (bf16)v.x; o[1] = (bf16)v.y; o[2] = (bf16)v.z; o[3] = (bf16)v.w;
    ((bf16x4*)d)[i] = o;
  }
}

// ---- one-shot weight conversion: 12 GRU mats (196608 ea) + linW (131072) ----
__global__ __launch_bounds__(256) void conv13(
    const float* s0, const float* s1, const float* s2, const float* s3,
    const float* s4, const float* s5, const float* s6, const float* s7,
    const float* s8, const float* s9, const float* s10, const float* s11,
    const float* s12, bf16* __restrict__ dst)
{
  const float* srcs[13] = {s0,s1,s2,s3,s4,s5,s6,s7,s8,s9,s10,s11,s12};
  int m = blockIdx.y;
  int n4 = (m == 12) ? 32768 : 49152;
  int i = blockIdx.x * 256 + threadIdx.x;
  if (i >= n4) return;
  float4 v = ((const float4*)srcs[m])[i];
  bf16x4 o;
  o[0] = (bf16)v.x; o[1] = (bf16)v.y; o[2] = (bf16)v.z; o[3] = (bf16)v.w;
  ((bf16x4*)(dst + (size_t)m * 196608))[i] = o;
}

// ---- bmod[g][i] = bi[i] + (i<512 ? bh[i] : 0)  for 6 GRUs. grid (3,6). ----
__global__ __launch_bounds__(256) void prep_bias(
    const float* b0i, const float* b0h, const float* b1i, const float* b1h,
    const float* b2i, const float* b2h, const float* b3i, const float* b3h,
    const float* b4i, const float* b4h, const float* b5i, const float* b5h,
    float* __restrict__ out)
{
  const float* bis[6] = {b0i,b1i,b2i,b3i,b4i,b5i};
  const float* bhs[6] = {b0h,b1h,b2h,b3h,b4h,b5h};
  int g = blockIdx.y;
  int i = blockIdx.x * 256 + threadIdx.x;
  if (i < 768)
    out[g * 768 + i] = bis[g][i] + (i < 512 ? bhs[g][i] : 0.f);
}

// ---------------------------------------------------------------------------
// xw = X(M x 256) @ W(768 x 256)^T + bias -> (M x 768) bf16.
// Wave handles 64 rows x 16 cols (weight frags reused 4x). grid.x=(M/64)*12.
// ---------------------------------------------------------------------------
__global__ __launch_bounds__(256) void xw_gemm(
    const bf16* __restrict__ X,
    const bf16* __restrict__ W0, const float* __restrict__ b0, bf16* __restrict__ o0,
    const bf16* __restrict__ W1, const float* __restrict__ b1, bf16* __restrict__ o1)
{
  const bf16* W = blockIdx.y ? W1 : W0;
  const float* bias = blockIdx.y ? b1 : b0;
  bf16* out = blockIdx.y ? o1 : o0;
  int wave = (int)blockIdx.x * 4 + (threadIdx.x >> 6);
  int g64 = wave / 48, ct = wave - g64 * 48;
  int lane = threadIdx.x & 63;
  int r16 = lane & 15, g4 = lane >> 4;
  const bf16* wp = W + (size_t)(ct * 16 + r16) * 256;
  const bf16* xb = X + ((size_t)g64 * 64 + r16) * 256;
  f32x4 a0 = {0,0,0,0}, a1 = {0,0,0,0}, a2 = {0,0,0,0}, a3 = {0,0,0,0};
#pragma unroll
  for (int kk = 0; kk < 8; kk++) {
    int k0 = kk * 32 + g4 * 8;
    bf16x8 wf = *(const bf16x8*)(wp + k0);
    a0 = mfma16(*(const bf16x8*)(xb + k0), wf, a0);
    a1 = mfma16(*(const bf16x8*)(xb + 4096 + k0), wf, a1);
    a2 = mfma16(*(const bf16x8*)(xb + 8192 + k0), wf, a2);
    a3 = mfma16(*(const bf16x8*)(xb + 12288 + k0), wf, a3);
  }
  float bv = bias[ct * 16 + r16];
#pragma unroll
  for (int rt = 0; rt < 4; rt++) {
    f32x4 ac = rt == 0 ? a0 : rt == 1 ? a1 : rt == 2 ? a2 : a3;
#pragma unroll
    for (int j = 0; j < 4; j++)
      out[(size_t)(g64 * 64 + rt * 16 + g4 * 4 + j) * 768 + ct * 16 + r16] = (bf16)(ac[j] + bv);
  }
}

// ---------------------------------------------------------------------------
// xw1 = emb[tok] @ W^T + bias (gather fused). blockIdx.y = t.
// ---------------------------------------------------------------------------
__global__ __launch_bounds__(256) void xw_gather_gemm(
    const int* __restrict__ tok, const bf16* __restrict__ embb,
    const bf16* __restrict__ W, const float* __restrict__ bias,
    bf16* __restrict__ out, int c)
{
  int t = blockIdx.y;
  int wave = (int)blockIdx.x * 4 + (threadIdx.x >> 6);
  int g64 = wave / 48, ct = wave - g64 * 48;
  int lane = threadIdx.x & 63;
  int r16 = lane & 15, g4 = lane >> 4;
  const bf16* wp = W + (size_t)(ct * 16 + r16) * 256;
  const bf16* ap[4];
#pragma unroll
  for (int rt = 0; rt < 4; rt++) {
    int n = g64 * 64 + rt * 16 + r16;
    int tk = tok[((n >> 5) << 10) + (t << 5) + (n & 31)];
    ap[rt] = embb + (size_t)tk * 256;
  }
  f32x4 a0 = {0,0,0,0}, a1 = {0,0,0,0}, a2 = {0,0,0,0}, a3 = {0,0,0,0};
#pragma unroll
  for (int kk = 0; kk < 8; kk++) {
    int k0 = kk * 32 + g4 * 8;
    bf16x8 wf = *(const bf16x8*)(wp + k0);
    a0 = mfma16(*(const bf16x8*)(ap[0] + k0), wf, a0);
    a1 = mfma16(*(const bf16x8*)(ap[1] + k0), wf, a1);
    a2 = mfma16(*(const bf16x8*)(ap[2] + k0), wf, a2);
    a3 = mfma16(*(const bf16x8*)(ap[3] + k0), wf, a3);
  }
  float bv = bias[ct * 16 + r16];
#pragma unroll
  for (int rt = 0; rt < 4; rt++) {
    f32x4 ac = rt == 0 ? a0 : rt == 1 ? a1 : rt == 2 ? a2 : a3;
#pragma unroll
    for (int j = 0; j < 4; j++)
      out[((size_t)t * c + g64 * 64 + rt * 16 + g4 * 4 + j) * 768 + ct * 16 + r16] = (bf16)(ac[j] + bv);
  }
}

// ---------------------------------------------------------------------------
// Persistent GRU v8. 512 thr = 8 waves; wave w owns 32 cols (2 tiles).
// Wh slice pinned in VGPRs (48 f32x4 = 192). Static LDS 82.7 KB (hbuf +
// TRIPLE-buffered xbuf, all genuinely used) -> 1 WG/CU -> 2 waves/SIMD;
// amdgpu_waves_per_eu(1,2) lowers the default 4-wave floor -> budget 256
// -> weights stay resident. xw staged via global_load_lds into per-wave
// self-regions xbuf[i%3][w][3][16][32]; counted vmcnt(3), never 0 mid-loop.
// ---------------------------------------------------------------------------
__global__ __launch_bounds__(512)
__attribute__((amdgpu_waves_per_eu(1, 2)))
void pgru(
    const bf16* __restrict__ xw0, const bf16* __restrict__ Wh0, const float* __restrict__ bh0,
    const bf16* __restrict__ xw1, const bf16* __restrict__ Wh1, const float* __restrict__ bh1,
    bf16* __restrict__ yout0, bf16* __restrict__ yout1, int ostride,
    const float* __restrict__ lng, const float* __restrict__ lnb,
    int steps, int Mtot, int rev0, int rev1)
{
  int dir = blockIdx.y;
  const bf16*  xw = dir ? xw1 : xw0;
  const bf16*  Wh = dir ? Wh1 : Wh0;
  const float* bh = dir ? bh1 : bh0;
  bf16* yout = dir ? yout1 : yout0;
  int rev = dir ? rev1 : rev0;

  __shared__ __align__(16) bf16 hbuf[16][280];          //  8960 B
  __shared__ __align__(16) bf16 xbuf[3][8][3][16][32];  // 73728 B -> 82688 B total

  int tid = threadIdx.x;
  int w = tid >> 6, lane = tid & 63, r16 = lane & 15, g4 = lane >> 4;
  int rowbase = (int)blockIdx.x * 16;
  int c0 = w * 32 + r16, c1 = c0 + 16;

  for (int i2 = tid; i2 < 560; i2 += 512) ((bf16x8*)hbuf)[i2] = (bf16x8){};

  // Wh slices -> registers, pinned (192 VGPR)
  f32x4 wr0[8], wz0[8], wn0[8], wr1[8], wz1[8], wn1[8];
  {
    const bf16* W0 = Wh + (size_t)c0 * 256;
    const bf16* W1 = Wh + (size_t)c1 * 256;
#pragma unroll
    for (int kk = 0; kk < 8; kk++) {
      int k0 = kk * 32 + g4 * 8;
      wr0[kk] = *(const f32x4*)(W0 + k0);          asm volatile("" : "+v"(wr0[kk]));
      wz0[kk] = *(const f32x4*)(W0 + 65536 + k0);  asm volatile("" : "+v"(wz0[kk]));
      wn0[kk] = *(const f32x4*)(W0 + 131072 + k0); asm volatile("" : "+v"(wn0[kk]));
      wr1[kk] = *(const f32x4*)(W1 + k0);          asm volatile("" : "+v"(wr1[kk]));
      wz1[kk] = *(const f32x4*)(W1 + 65536 + k0);  asm volatile("" : "+v"(wz1[kk]));
      wn1[kk] = *(const f32x4*)(W1 + 131072 + k0); asm volatile("" : "+v"(wn1[kk]));
    }
  }
  float bhn0 = bh[c0 + 512], bhn1 = bh[c1 + 512];

  // stage step st into xbuf[b][w]: 3 DMAs (one per gate region [16][32]).
  int m_ = lane >> 2;
  int k_ = (lane & 3) * 8;
  auto stage = [&](int b, int st) {
    const bf16* s = xw + ((size_t)st * Mtot + rowbase + m_) * 768 + w * 32 + k_;
    gload16(s,       &xbuf[b][w][0][0][0]);
    gload16(s + 256, &xbuf[b][w][1][0][0]);
    gload16(s + 512, &xbuf[b][w][2][0][0]);
  };
  stage(0, rev ? steps - 1 : 0);
  wg_barrier();   // hbuf zero-init visible (xbuf readiness via vmcnt)

  for (int i = 0; i < steps; i++) {
    int cur = i % 3;
    int st = rev ? steps - 1 - i : i;
    if (i + 1 < steps) {
      stage((i + 1) % 3, rev ? steps - 2 - i : i + 1);
      asm volatile("s_waitcnt vmcnt(3)" ::: "memory");   // my xbuf[cur] ready
    } else {
      asm volatile("s_waitcnt vmcnt(0)" ::: "memory");
    }
    __builtin_amdgcn_sched_barrier(0);

    float hn0[4], hn1[4];
    {
      f32x4 a0 = {0,0,0,0}, a1 = {0,0,0,0}, a2 = {0,0,0,0};
#pragma unroll
      for (int kk = 0; kk < 8; kk++) {
        bf16x8 a = *(const bf16x8*)&hbuf[r16][kk * 32 + g4 * 8];
        a0 = mfma16(a, asbf(wr0[kk]), a0);
        a1 = mfma16(a, asbf(wz0[kk]), a1);
        a2 = mfma16(a, asbf(wn0[kk]), a2);
      }
#pragma unroll
      for (int j = 0; j < 4; j++) {
        int m = g4 * 4 + j;
        float r = sigm((float)xbuf[cur][w][0][m][r16] + a0[j]);
        float z = sigm((float)xbuf[cur][w][1][m][r16] + a1[j]);
        float n = tanhf((float)xbuf[cur][w][2][m][r16] + r * (a2[j] + bhn0));
        hn0[j] = (1.f - z) * n + z * (float)hbuf[m][c0];
      }
    }
    {
      f32x4 a0 = {0,0,0,0}, a1 = {0,0,0,0}, a2 = {0,0,0,0};
#pragma unroll
      for (int kk = 0; kk < 8; kk++) {
        bf16x8 a = *(const bf16x8*)&hbuf[r16][kk * 32 + g4 * 8];
        a0 = mfma16(a, asbf(wr1[kk]), a0);
        a1 = mfma16(a, asbf(wz1[kk]), a1);
        a2 = mfma16(a, asbf(wn1[kk]), a2);
      }
#pragma unroll
      for (int j = 0; j < 4; j++) {
        int m = g4 * 4 + j;
        float r = sigm((float)xbuf[cur][w][0][m][r16 + 16] + a0[j]);
        float z = sigm((float)xbuf[cur][w][1][m][r16 + 16] + a1[j]);
        float n = tanhf((float)xbuf[cur][w][2][m][r16 + 16] + r * (a2[j] + bhn1));
        hn1[j] = (1.f - z) * n + z * (float)hbuf[m][c1];
      }
    }
    wg_barrier();                    // all hbuf / xbuf[cur] reads done WG-wide
#pragma unroll
    for (int j = 0; j < 4; j++) {
      int m = g4 * 4 + j;
      hbuf[m][c0] = (bf16)hn0[j];
      hbuf[m][c1] = (bf16)hn1[j];
    }
    if (!lng) {
#pragma unroll
      for (int j = 0; j < 4; j++) {
        size_t ro = ((size_t)st * Mtot + rowbase + g4 * 4 + j) * ostride;
        yout[ro + c0] = (bf16)hn0[j];
        yout[ro + c1] = (bf16)hn1[j];
      }
    }
    wg_barrier();                    // h_{i+1} visible
    if (lng) {
      // fused LN(256); recurrence keeps raw h. wave -> rows 2w, 2w+1
#pragma unroll
      for (int rr = 0; rr < 2; rr++) {
        int r = w * 2 + rr;
        bf16x4 v4 = *(const bf16x4*)&hbuf[r][lane * 4];
        float v[4]; float sm = 0.f, sq = 0.f;
#pragma unroll
        for (int j = 0; j < 4; j++) { v[j] = (float)v4[j]; sm += v[j]; sq += v[j] * v[j]; }
        for (int msk = 32; msk; msk >>= 1) { sm += __shfl_xor(sm, msk); sq += __shfl_xor(sq, msk); }
        float mu  = sm * (1.f / 256.f);
        float var = sq * (1.f / 256.f) - mu * mu;
        float inv = rsqrtf(fmaxf(var, 0.f) + 1e-5f);
        bf16x4 o;
#pragma unroll
        for (int j = 0; j < 4; j++)
          o[j] = (bf16)((v[j] - mu) * inv * lng[lane * 4 + j] + lnb[lane * 4 + j]);
        *(bf16x4*)&yout[((size_t)st * Mtot + rowbase + r) * ostride + lane * 4] = o;
      }
    }
  }
}

// ---------------------------------------------------------------------------
// Sentence tail, t-parallel: block (r-tile, tg) accumulates 4 t's of
// tanh(LN512(hf||hb) @ linW^T + b) into part[tg] (f32). grid (c/16, 8).
// ---------------------------------------------------------------------------
__global__ __launch_bounds__(256) void sent_tail_part(
    const bf16* __restrict__ hf, const bf16* __restrict__ hb,
    const float* __restrict__ gam, const float* __restrict__ bet,
    const bf16* __restrict__ W, const float* __restrict__ bias,
    float* __restrict__ part, int c)
{
  int wave = threadIdx.x >> 6;
  int lane = threadIdx.x & 63;
  int r16 = lane & 15, g4 = lane >> 4;
  int r0 = (int)blockIdx.x << 4;
  int tg = blockIdx.y;
  size_t rowoff = (size_t)(r0 + r16) * 256;

  f32x4 ms0 = {0,0,0,0}, ms1 = {0,0,0,0}, ms2 = {0,0,0,0}, ms3 = {0,0,0,0};

  for (int tt = 0; tt < 4; tt++) {
    int t = tg * 4 + tt;
    const bf16* pf = hf + (size_t)t * c * 256 + rowoff;
    const bf16* pb = hb + (size_t)t * c * 256 + rowoff;
    bf16x8 xv[16];
    float s = 0.f, sq = 0.f;
#pragma unroll
    for (int kk = 0; kk < 16; kk++) {
      int k0 = kk * 32 + g4 * 8;
      xv[kk] = (kk < 8) ? *(const bf16x8*)(pf + k0) : *(const bf16x8*)(pb + k0 - 256);
#pragma unroll
      for (int j = 0; j < 8; j++) { float f = (float)xv[kk][j]; s += f; sq += f * f; }
    }
    s  += __shfl_xor(s, 16);  s  += __shfl_xor(s, 32);
    sq += __shfl_xor(sq, 16); sq += __shfl_xor(sq, 32);
    float mu  = s * (1.f / 512.f);
    float var = sq * (1.f / 512.f) - mu * mu;
    float inv = rsqrtf(fmaxf(var, 0.f) + 1e-5f);
#pragma unroll
    for (int kk = 0; kk < 16; kk++) {
      int k0 = kk * 32 + g4 * 8;
      float ga[8], be[8];
      *(float4*)(ga)     = *(const float4*)(gam + k0);
      *(float4*)(ga + 4) = *(const float4*)(gam + k0 + 4);
      *(float4*)(be)     = *(const float4*)(bet + k0);
      *(float4*)(be + 4) = *(const float4*)(bet + k0 + 4);
#pragma unroll
      for (int j = 0; j < 8; j++)
        xv[kk][j] = (bf16)(((float)xv[kk][j] - mu) * inv * ga[j] + be[j]);
    }
#pragma unroll
    for (int tc = 0; tc < 4; tc++) {
      int cj = wave * 64 + tc * 16;
      const bf16* wp = W + (size_t)(cj + r16) * 512;
      f32x4 acc = {0,0,0,0};
#pragma unroll
      for (int kk = 0; kk < 16; kk++)
        acc = mfma16(xv[kk], *(const bf16x8*)(wp + kk * 32 + g4 * 8), acc);
      float bb = bias[cj + r16];
      f32x4* msp = (tc == 0) ? &ms0 : (tc == 1) ? &ms1 : (tc == 2) ? &ms2 : &ms3;
#pragma unroll
      for (int j = 0; j < 4; j++) (*msp)[j] += tanhf(acc[j] + bb);
    }
  }
#pragma unroll
  for (int tc = 0; tc < 4; tc++) {
    int cj = wave * 64 + tc * 16;
    f32x4 ms = (tc == 0) ? ms0 : (tc == 1) ? ms1 : (tc == 2) ? ms2 : ms3;
#pragma unroll
    for (int j = 0; j < 4; j++)
      part[((size_t)tg * c + r0 + g4 * 4 + j) * 256 + cj + r16] = ms[j];
  }
}

// sum 8 partials, scale 1/32, write bf16. grid = c blocks x 256 thr.
__global__ __launch_bounds__(256) void tail_reduce(
    const float* __restrict__ part, bf16* __restrict__ out, int c)
{
  int idx = blockIdx.x * 256 + threadIdx.x;
  float s = 0.f;
#pragma unroll
  for (int g = 0; g < 8; g++) s += part[(size_t)g * c * 256 + idx];
  out[idx] = (bf16)(s * 0.03125f);
}

// ---------------------------------------------------------------------------
// Fused LN(512) + sigmoid head: out(3072x2 f32). Wave per row.
// ---------------------------------------------------------------------------
__global__ __launch_bounds__(256) void ln_out_head(
    const bf16* __restrict__ X, const float* __restrict__ lng, const float* __restrict__ lnb,
    const float* __restrict__ W, const float* __restrict__ bias, float* __restrict__ out)
{
  int w = threadIdx.x >> 6, lane = threadIdx.x & 63;
  int row = (int)blockIdx.x * 4 + w;
  bf16x8 v8 = *(const bf16x8*)&X[(size_t)row * 512 + lane * 8];
  float v[8]; float sm = 0.f, sq = 0.f;
#pragma unroll
  for (int j = 0; j < 8; j++) { v[j] = (float)v8[j]; sm += v[j]; sq += v[j] * v[j]; }
  for (int msk = 32; msk; msk >>= 1) { sm += __shfl_xor(sm, msk); sq += __shfl_xor(sq, msk); }
  float mu  = sm * (1.f / 512.f);
  float var = sq * (1.f / 512.f) - mu * mu;
  float inv = rsqrtf(fmaxf(var, 0.f) + 1e-5f);
  float a0 = 0.f, a1 = 0.f;
  int base = lane * 8;
#pragma unroll
  for (int j = 0; j < 8; j++) {
    float y = (v[j] - mu) * inv * lng[base + j] + lnb[base + j];
    a0 += y * W[base + j];
    a1 += y * W[512 + base + j];
  }
  for (int msk = 32; msk; msk >>= 1) { a0 += __shfl_xor(a0, msk); a1 += __shfl_xor(a1, msk); }
  if (lane == 0) {
    out[(size_t)row * 2 + 0] = sigm(a0 + bias[0]);
    out[(size_t)row * 2 + 1] = sigm(a1 + bias[1]);
  }
}

// ---------------------------------------------------------------------------
extern "C" void kernel_launch(void* const* d_in, const int* in_sizes, int n_in,
                              void* d_out, int out_size, void* d_ws, size_t ws_size,
                              hipStream_t stream)
{
  (void)in_sizes; (void)n_in; (void)out_size;
  const int*   tokens = (const int*)d_in[0];
  const float* emb    = (const float*)d_in[1];
  auto fp = [&](int i) { return (const float*)d_in[i]; };
  const float *s_WiF = fp(2),  *s_WhF = fp(3),  *s_biF = fp(4),  *s_bhF = fp(5);
  const float *s_lnF_g = fp(6), *s_lnF_b = fp(7);
  const float *s_Wi_f = fp(8),  *s_Wh_f = fp(9),  *s_bi_f = fp(10), *s_bh_f = fp(11);
  const float *s_Wi_b = fp(12), *s_Wh_b = fp(13), *s_bi_b = fp(14), *s_bh_b = fp(15);
  const float *s_ln_g = fp(16), *s_ln_b = fp(17), *s_linW = fp(18), *s_linb = fp(19);
  const float *dWiF = fp(20), *dWhF = fp(21), *dbiF = fp(22), *dbhF = fp(23);
  const float *d_lnF_g = fp(24), *d_lnF_b = fp(25);
  const float *dWi_f = fp(26), *dWh_f = fp(27), *dbi_f = fp(28), *dbh_f = fp(29);
  const float *dWi_b = fp(30), *dWh_b = fp(31), *dbi_b = fp(32), *dbh_b = fp(33);
  const float *d_ln_g = fp(34), *d_ln_b = fp(35), *out_W = fp(36), *out_b = fp(37);

  const int T = 32, S = 96;
  const int GW = 196608;

  // ---- converted bf16 weights + emb + folded biases ----
  bf16* wc = (bf16*)d_ws;
  bf16 *c_sWiF = wc,         *c_sWhF = wc + GW;
  bf16 *c_sWif = wc + 2*GW,  *c_sWhf = wc + 3*GW;
  bf16 *c_sWib = wc + 4*GW,  *c_sWhb = wc + 5*GW;
  bf16 *c_dWiF = wc + 6*GW,  *c_dWhF = wc + 7*GW;
  bf16 *c_dWif = wc + 8*GW,  *c_dWhf = wc + 9*GW;
  bf16 *c_dWib = wc + 10*GW, *c_dWhb = wc + 11*GW;
  bf16 *c_linW = wc + 12*GW;
  const size_t WB = (size_t)(12 * GW + 131072) * 2;       // 4,980,736
  bf16* embb = (bf16*)((char*)d_ws + WB);                 // 32000x256 bf16
  const size_t EB = (size_t)32000 * 256 * 2;              // 16,384,000
  float* bmod = (float*)((char*)d_ws + WB + EB);          // 6 x 768 f32
  const size_t BMB = 6 * 768 * 4;                         // 18,432

  conv13<<<dim3(192, 13), 256, 0, stream>>>(
      s_WiF, s_WhF, s_Wi_f, s_Wh_f, s_Wi_b, s_Wh_b,
      dWiF, dWhF, dWi_f, dWh_f, dWi_b, dWh_b, s_linW, wc);
  cvt_bf16<<<8000, 256, 0, stream>>>(emb, embb, 2048000);
  prep_bias<<<dim3(3, 6), 256, 0, stream>>>(
      s_biF, s_bhF, s_bi_f, s_bh_f, s_bi_b, s_bh_b,
      dbiF, dbhF, dbi_f, dbh_f, dbi_b, dbh_b, bmod);
  const float *bm_sF = bmod, *bm_sf = bmod + 768, *bm_sb = bmod + 1536;
  const float *bm_dF = bmod + 2304, *bm_df = bmod + 3072, *bm_db = bmod + 3840;

  // ---- fixed doc-side buffers ----
  char* ws = (char*)d_ws + WB + EB + BMB;
  bf16* store = (bf16*)ws;                           // (3072, 256)
  bf16* yd1ln = store + (size_t)3072 * 256;          // (3072, 256)
  bf16* ybid  = yd1ln + (size_t)3072 * 256;          // (3072, 512)
  bf16* xw_u  = ybid  + (size_t)3072 * 512;          // (3072, 768)
  bf16* xwdf  = xw_u  + (size_t)3072 * 768;
  bf16* xwdb  = xwdf  + (size_t)3072 * 768;
  const size_t fixedB = WB + EB + BMB
      + ((size_t)3072 * 256 * 2 + (size_t)3072 * 512 + (size_t)3 * 3072 * 768) * 2;

  // ---- sentence chunk size (rows; multiple of 64) ----
  // per-row: xw 49152 + y1ln 16384 + hf 16384 + hb 16384 = 98304 B
  int c = 3072;
  while (c > 192 && fixedB + (size_t)98304 * c > ws_size) c >>= 1;
  char* cb = (char*)d_ws + fixedB;
  bf16*  xw   = (bf16*)cb;                           // (T*c, 768), reused 3x
  bf16*  y1ln = (bf16*)(cb + (size_t)49152 * c);     // (T*c, 256)
  bf16*  hf   = (bf16*)(cb + (size_t)65536 * c);     // (T*c, 256)
  bf16*  hb   = (bf16*)(cb + (size_t)81920 * c);     // (T*c, 256)
  float* part = (float*)cb;                          // (8, c, 256) f32, alias xw

  // ---- sentence encoder, chunked ----
  for (int base = 0; base < 3072; base += c) {
    const int* tkb = tokens + (size_t)base * 32;
    xw_gather_gemm<<<dim3((c / 64) * 12, T), 256, 0, stream>>>(
        tkb, embb, c_sWiF, bm_sF, xw, c);
    pgru<<<dim3(c / 16, 1), 512, 0, stream>>>(
        xw, c_sWhF, s_bhF, nullptr, nullptr, nullptr,
        y1ln, nullptr, 256, s_lnF_g, s_lnF_b, T, c, 0, 0);
    xw_gemm<<<dim3((T * c / 64) * 12, 1), 256, 0, stream>>>(
        y1ln, c_sWif, bm_sf, xw, nullptr, nullptr, nullptr);
    pgru<<<dim3(c / 16, 1), 512, 0, stream>>>(
        xw, c_sWhf, s_bh_f, nullptr, nullptr, nullptr,
        hf, nullptr, 256, nullptr, nullptr, T, c, 0, 0);
    xw_gemm<<<dim3((T * c / 64) * 12, 1), 256, 0, stream>>>(
        y1ln, c_sWib, bm_sb, xw, nullptr, nullptr, nullptr);
    pgru<<<dim3(c / 16, 1), 512, 0, stream>>>(
        xw, c_sWhb, s_bh_b, nullptr, nullptr, nullptr,
        hb, nullptr, 256, nullptr, nullptr, T, c, 1, 0);
    sent_tail_part<<<dim3(c / 16, 8), 256, 0, stream>>>(
        hf, hb, s_ln_g, s_ln_b, c_linW, s_linb, part, c);
    tail_reduce<<<c, 256, 0, stream>>>(part, store + (size_t)base * 256, c);
  }

  // ---- document encoder ----
  xw_gemm<<<dim3((3072 / 64) * 12, 1), 256, 0, stream>>>(
      store, c_dWiF, bm_dF, xw_u, nullptr, nullptr, nullptr);
  pgru<<<dim3(2, 1), 512, 0, stream>>>(
      xw_u, c_dWhF, dbhF, nullptr, nullptr, nullptr,
      yd1ln, nullptr, 256, d_lnF_g, d_lnF_b, S, 32, 0, 0);
  xw_gemm<<<dim3((3072 / 64) * 12, 2), 256, 0, stream>>>(
      yd1ln, c_dWif, bm_df, xwdf, c_dWib, bm_db, xwdb);
  pgru<<<dim3(2, 2), 512, 0, stream>>>(
      xwdf, c_dWhf, dbh_f, xwdb, c_dWhb, dbh_b,
      ybid, ybid + 256, 512, nullptr, nullptr, S, 32, 0, 1);
  ln_out_head<<<768, 256, 0, stream>>>(ybid, d_ln_g, d_ln_b, out_W, out_b,
                                       (float*)d_out);
}